// Round 7
// baseline (621.168 us; speedup 1.0000x reference)
//
#include <hip/hip_runtime.h>
#include <hip/hip_bf16.h>

typedef unsigned short u16;
typedef __bf16 bf16x8 __attribute__((ext_vector_type(8)));
typedef float f32x4 __attribute__((ext_vector_type(4)));
typedef u16 ushort8 __attribute__((ext_vector_type(8)));

#define TSEQ 2048
#define NHEAD 16

#define GLD16(gp, lp) __builtin_amdgcn_global_load_lds( \
    (__attribute__((address_space(1))) void*)(gp), \
    (__attribute__((address_space(3))) void*)(lp), 16, 0, 0)

static __device__ __forceinline__ float bf2f(u16 u) {
  unsigned int x = ((unsigned int)u) << 16;
  union { unsigned int i; float f; } c; c.i = x; return c.f;
}
static __device__ __forceinline__ u16 f2bf(float f) {
  union { float f; unsigned int i; } c; c.f = f;
  unsigned int x = c.i;
  unsigned int r = (x + 0x7FFFu + ((x >> 16) & 1u)) >> 16;
  return (u16)r;
}
static __device__ __forceinline__ void st_out(u16* p, float v) { *p = f2bf(v); }
static __device__ __forceinline__ void st_out(float* p, float v) { *p = v; }

// ---------------- convert x (f32 -> bf16), 8 elems/thread ----------------
__global__ __launch_bounds__(256) void k_conv_x(const float* __restrict__ x, u16* __restrict__ xb) {
  size_t i = ((size_t)blockIdx.x * 256 + threadIdx.x) * 8;
  float4 a = *(const float4*)(x + i);
  float4 b = *(const float4*)(x + i + 4);
  ushort8 o;
  o[0] = f2bf(a.x); o[1] = f2bf(a.y); o[2] = f2bf(a.z); o[3] = f2bf(a.w);
  o[4] = f2bf(b.x); o[5] = f2bf(b.y); o[6] = f2bf(b.z); o[7] = f2bf(b.w);
  *(ushort8*)(xb + i) = o;
}

// -------- transpose+convert weight: src f32 [R,Cc] -> dst bf16, dst[c][r]=src[r][c], zero-padded --------
// grid: (Rpad/32, Cpad/32); loads guarded by (r<R && c<Cc), stores unguarded.
__global__ __launch_bounds__(256) void k_tconv(const float* __restrict__ src, u16* __restrict__ dst,
                                               int R, int Cc, int Rpad) {
  __shared__ float sm[32][33];
  int tx = threadIdx.x & 31, ty = threadIdx.x >> 5;
  int r0 = blockIdx.x * 32, c0 = blockIdx.y * 32;
#pragma unroll
  for (int i = 0; i < 4; i++) {
    int r = r0 + ty + 8 * i;
    int c = c0 + tx;
    sm[ty + 8 * i][tx] = (r < R && c < Cc) ? src[(size_t)r * Cc + c] : 0.f;
  }
  __syncthreads();
#pragma unroll
  for (int i = 0; i < 4; i++) {
    int c = c0 + ty + 8 * i;
    dst[(size_t)c * Rpad + r0 + tx] = f2bf(sm[tx][ty + 8 * i]);
  }
}

// ---------------- gate = 2*sigmoid(x[:, :32] @ w_ve_gate) ----------------
__global__ __launch_bounds__(256) void k_gate(const float* __restrict__ x, const float* __restrict__ wg,
                                              float* __restrict__ gate) {
  int idx = blockIdx.x * 256 + threadIdx.x; // m*16 + h
  int m = idx >> 4, h = idx & 15;
  const float* xr = x + (size_t)m * 2048;
  float s = 0.f;
#pragma unroll
  for (int j = 0; j < 32; j++) s += xr[j] * wg[j * 16 + h];
  gate[idx] = 2.f / (1.f + __expf(-s));
}

// ---------------- 64x64 GEMM (kept for the tiny N=64 k_rope projection) ----------------
template <typename OT>
__global__ __launch_bounds__(256) void k_gemm_bt(const u16* __restrict__ A, const u16* __restrict__ BT,
                                                 OT* __restrict__ C, int M, int N, int K) {
  __shared__ __align__(16) u16 As[64][40];
  __shared__ __align__(16) u16 Bs[64][40];
  int t = threadIdx.x;
  int wid = t >> 6, lane = t & 63;
  int wr = (wid >> 1) * 32, wc = (wid & 1) * 32;
  int m0 = blockIdx.y * 64, n0 = blockIdx.x * 64;
  int lrow = t >> 2, lk = (t & 3) * 8;
  const u16* Ag = A + (size_t)(m0 + lrow) * K + lk;
  const u16* Bg = BT + (size_t)(n0 + lrow) * K + lk;
  f32x4 acc00 = {0,0,0,0}, acc01 = {0,0,0,0}, acc10 = {0,0,0,0}, acc11 = {0,0,0,0};
  int fr = lane & 15, fo = (lane >> 4) * 8;
  for (int k0 = 0; k0 < K; k0 += 32) {
    *(ushort8*)&As[lrow][lk] = *(const ushort8*)(Ag + k0);
    *(ushort8*)&Bs[lrow][lk] = *(const ushort8*)(Bg + k0);
    __syncthreads();
    bf16x8 a0 = *(const bf16x8*)&As[wr + fr][fo];
    bf16x8 a1 = *(const bf16x8*)&As[wr + 16 + fr][fo];
    bf16x8 b0 = *(const bf16x8*)&Bs[wc + fr][fo];
    bf16x8 b1 = *(const bf16x8*)&Bs[wc + 16 + fr][fo];
    acc00 = __builtin_amdgcn_mfma_f32_16x16x32_bf16(a0, b0, acc00, 0, 0, 0);
    acc01 = __builtin_amdgcn_mfma_f32_16x16x32_bf16(a0, b1, acc01, 0, 0, 0);
    acc10 = __builtin_amdgcn_mfma_f32_16x16x32_bf16(a1, b0, acc10, 0, 0, 0);
    acc11 = __builtin_amdgcn_mfma_f32_16x16x32_bf16(a1, b1, acc11, 0, 0, 0);
    __syncthreads();
  }
  int cr = (lane >> 4) * 4, cc = lane & 15;
#pragma unroll
  for (int r = 0; r < 4; r++) {
    size_t row0 = (size_t)(m0 + wr + cr + r);
    size_t row1 = row0 + 16;
    st_out(&C[row0 * N + n0 + wc + cc],      acc00[r]);
    st_out(&C[row0 * N + n0 + wc + 16 + cc], acc01[r]);
    st_out(&C[row1 * N + n0 + wc + cc],      acc10[r]);
    st_out(&C[row1 * N + n0 + wc + 16 + cc], acc11[r]);
  }
}

// ---------------- 128x128 GEMM, m97-style: linear LDS + global_load_lds w16, BK=32 ----------------
// M%128==0, N%128==0, K%32==0. 256 threads = 4 waves, each computes a 64x64 quadrant (4x4 frags).
template <typename OT>
__global__ __launch_bounds__(256) void k_gemm128(const u16* __restrict__ A, const u16* __restrict__ BT,
                                                 OT* __restrict__ C, int M, int N, int K) {
  __shared__ __align__(16) u16 As[128 * 32];
  __shared__ __align__(16) u16 Bs[128 * 32];
  int t = threadIdx.x;
  int wid = t >> 6, lane = t & 63;
  int m0 = blockIdx.y * 128, n0 = blockIdx.x * 128;
  // staging: wave stages chunks c0,c0+1 of A and B (chunk = 16 rows x 32 cols = 1KB)
  int c0 = wid * 2;
  int srow0 = c0 * 16 + (lane >> 2);
  int scol = (lane & 3) * 8;
  const u16* Ag0 = A + (size_t)(m0 + srow0) * K + scol;
  const u16* Ag1 = A + (size_t)(m0 + srow0 + 16) * K + scol;
  const u16* Bg0 = BT + (size_t)(n0 + srow0) * K + scol;
  const u16* Bg1 = BT + (size_t)(n0 + srow0 + 16) * K + scol;
  u16* Al0 = &As[c0 * 512];        // wave-uniform LDS bases (HW adds lane*16B)
  u16* Al1 = &As[c0 * 512 + 512];
  u16* Bl0 = &Bs[c0 * 512];
  u16* Bl1 = &Bs[c0 * 512 + 512];
  int wr = (wid >> 1) * 64, wc = (wid & 1) * 64;
  int fr = lane & 15, fo = (lane >> 4) * 8;
  f32x4 acc[4][4];
#pragma unroll
  for (int m = 0; m < 4; m++)
#pragma unroll
    for (int n = 0; n < 4; n++) acc[m][n] = (f32x4){0, 0, 0, 0};
  for (int k0 = 0; k0 < K; k0 += 32) {
    GLD16(Ag0 + k0, Al0);
    GLD16(Ag1 + k0, Al1);
    GLD16(Bg0 + k0, Bl0);
    GLD16(Bg1 + k0, Bl1);
    __syncthreads();
    bf16x8 af[4], bf[4];
#pragma unroll
    for (int m = 0; m < 4; m++) af[m] = *(const bf16x8*)&As[(wr + m * 16 + fr) * 32 + fo];
#pragma unroll
    for (int n = 0; n < 4; n++) bf[n] = *(const bf16x8*)&Bs[(wc + n * 16 + fr) * 32 + fo];
#pragma unroll
    for (int m = 0; m < 4; m++)
#pragma unroll
      for (int n = 0; n < 4; n++)
        acc[m][n] = __builtin_amdgcn_mfma_f32_16x16x32_bf16(af[m], bf[n], acc[m][n], 0, 0, 0);
    __syncthreads();
  }
  int cr = (lane >> 4) * 4, cc = lane & 15;
#pragma unroll
  for (int m = 0; m < 4; m++)
#pragma unroll
    for (int n = 0; n < 4; n++)
#pragma unroll
      for (int r = 0; r < 4; r++)
        st_out(&C[(size_t)(m0 + wr + m * 16 + cr + r) * N + n0 + wc + n * 16 + cc], acc[m][n][r]);
}

// ---------------- build K: concat(k_nope, rope(k_rope)), rmsnorm, -> kf[b][h][t][128] bf16 ----------------
__global__ __launch_bounds__(256) void k_build_k(const u16* __restrict__ kv, const u16* __restrict__ kr,
                                                 const float* __restrict__ cosp, const float* __restrict__ sinp,
                                                 u16* __restrict__ kf) {
  int wid = threadIdx.x >> 6, lane = threadIdx.x & 63;
  int idx = blockIdx.x * 4 + wid; // m*16 + h
  int m = idx >> 4, h = idx & 15;
  int d0 = lane * 2;
  float v[2];
#pragma unroll
  for (int e = 0; e < 2; e++) {
    int d = d0 + e;
    float val;
    if (d < 64) {
      val = bf2f(kv[(size_t)m * 3072 + h * 192 + d]);
    } else {
      int dd = d - 64, i = dd & 31;
      float c = cosp[m * 32 + i], s = sinp[m * 32 + i];
      float x1 = bf2f(kr[(size_t)m * 64 + i]), x2 = bf2f(kr[(size_t)m * 64 + 32 + i]);
      val = (dd < 32) ? (x1 * c + x2 * s) : (x2 * c - x1 * s);
    }
    v[e] = val;
  }
  float ss = v[0] * v[0] + v[1] * v[1];
#pragma unroll
  for (int o = 1; o < 64; o <<= 1) ss += __shfl_xor(ss, o, 64);
  float rms = rsqrtf(ss * (1.f / 128.f) + 1.1920929e-7f);
  int b = m >> 11, tt = m & 2047;
  size_t base = ((size_t)(b * NHEAD + h) * TSEQ + tt) * 128 + d0;
  kf[base] = f2bf(v[0] * rms);
  kf[base + 1] = f2bf(v[1] * rms);
}

// ---------------- build Q: concat(q_nope, rope(q_rope)), rmsnorm * 1/sqrt(128) ----------------
__global__ __launch_bounds__(256) void k_build_q(const u16* __restrict__ qr,
                                                 const float* __restrict__ cosp, const float* __restrict__ sinp,
                                                 u16* __restrict__ qf) {
  int wid = threadIdx.x >> 6, lane = threadIdx.x & 63;
  int idx = blockIdx.x * 4 + wid; // m*16 + h
  int m = idx >> 4, h = idx & 15;
  size_t bin = (size_t)m * 2048 + h * 128;
  int d0 = lane * 2;
  float v[2];
#pragma unroll
  for (int e = 0; e < 2; e++) {
    int d = d0 + e;
    float val;
    if (d < 64) {
      val = bf2f(qr[bin + d]);
    } else {
      int dd = d - 64, i = dd & 31;
      float c = cosp[m * 32 + i], s = sinp[m * 32 + i];
      float x1 = bf2f(qr[bin + 64 + i]), x2 = bf2f(qr[bin + 96 + i]);
      val = (dd < 32) ? (x1 * c + x2 * s) : (x2 * c - x1 * s);
    }
    v[e] = val;
  }
  float ss = v[0] * v[0] + v[1] * v[1];
#pragma unroll
  for (int o = 1; o < 64; o <<= 1) ss += __shfl_xor(ss, o, 64);
  float rms = rsqrtf(ss * (1.f / 128.f) + 1.1920929e-7f) * 0.08838834764831845f;
  int b = m >> 11, tt = m & 2047;
  size_t base = ((size_t)(b * NHEAD + h) * TSEQ + tt) * 128 + d0;
  qf[base] = f2bf(v[0] * rms);
  qf[base + 1] = f2bf(v[1] * rms);
}

// ---------------- build V: v = kv_v + gate*ve, transpose -> vt[b][h][128][t] bf16 ----------------
__global__ __launch_bounds__(256) void k_build_v(const u16* __restrict__ kv, const float* __restrict__ ve,
                                                 const float* __restrict__ gate, u16* __restrict__ vt) {
  __shared__ __align__(16) char sm[128 * 128]; // [128 d][64 t] u16, XOR-swizzled rows
  int bh = blockIdx.x >> 5, t0 = (blockIdx.x & 31) * 64;
  int b = bh >> 4, h = bh & 15;
  int tt = threadIdx.x >> 2, dp = (threadIdx.x & 3) * 32;
  int m = b * TSEQ + t0 + tt;
  float g = gate[m * 16 + h];
  const u16* kvp = kv + (size_t)m * 3072 + h * 192 + 64 + dp;
  const float* vep = ve + (size_t)m * 2048 + h * 128 + dp;
  ushort8 kvv[4];
  float4 vev[8];
#pragma unroll
  for (int u = 0; u < 4; u++) kvv[u] = *(const ushort8*)(kvp + u * 8);
#pragma unroll
  for (int u = 0; u < 8; u++) vev[u] = *(const float4*)(vep + u * 4);
#pragma unroll
  for (int j = 0; j < 32; j++) {
    float vvf = ((const float*)&vev[j >> 2])[j & 3];
    float v = bf2f(kvv[j >> 3][j & 7]) + g * vvf;
    int row = dp + j;
    int a = row * 128 + tt * 2;
    *(u16*)(sm + (a ^ ((row & 7) << 4))) = f2bf(v);
  }
  __syncthreads();
  int d = threadIdx.x >> 1, tp = (threadIdx.x & 1) * 32;
  u16* dst = vt + ((size_t)bh * 128 + d) * TSEQ + t0 + tp;
#pragma unroll
  for (int j = 0; j < 32; j += 8) {
    int a = d * 128 + (tp + j) * 2;
    *(ushort8*)(dst + j) = *(const ushort8*)(sm + (a ^ ((d & 7) << 4)));
  }
}

// ---------------- flash attention, 4-way key-split: 4 waves/block, strided K-tiles, LDS merge ----------------
// Block = one (bh, qt) task. Wave w handles tiles it = w, w+4, ... Partials merged via LDS.
__global__ __launch_bounds__(256) void k_attn(const u16* __restrict__ qf, const u16* __restrict__ kf,
                                              const u16* __restrict__ vt, u16* __restrict__ y) {
  // OL[4][16][132] f32 (33792 B) + ML[4][16] + LL[4][16]; P-scratch (4x2KB) aliases OL (barrier-separated)
  __shared__ __align__(16) char smraw[33792 + 256 + 256];
  float* OL = (float*)smraw;                      // [w][lr][d] stride 132
  float* ML = (float*)(smraw + 33792);            // [w*16 + lr]
  float* LL = (float*)(smraw + 33792 + 256);
  int tid = threadIdx.x;
  int wid = tid >> 6, lane = tid & 63;
  u16* plds = (u16*)smraw + wid * 1024;           // 16 rows x 64 cols bf16, XOR-swizzled
  int bh = blockIdx.x & 31;
  int qt = 127 - (blockIdx.x >> 5);               // heavy-first
  int q0 = qt * 16;
  const u16* qp = qf + (size_t)bh * TSEQ * 128;
  const u16* kp = kf + (size_t)bh * TSEQ * 128;
  const u16* vp = vt + (size_t)bh * 128 * TSEQ;
  int fr = lane & 15, fo = (lane >> 4) * 8;
  bf16x8 qfr[4];
#pragma unroll
  for (int kc = 0; kc < 4; kc++)
    qfr[kc] = *(const bf16x8*)(qp + (size_t)(q0 + fr) * 128 + kc * 32 + fo);
  f32x4 oacc[8];
#pragma unroll
  for (int nd = 0; nd < 8; nd++) oacc[nd] = (f32x4){0, 0, 0, 0};
  float mrow[4] = {-1e30f, -1e30f, -1e30f, -1e30f};
  float srow[4] = {0, 0, 0, 0};
  int qgb = q0 + (lane >> 4) * 4;
  int lrb = (lane >> 4) * 4;
  int nfull = qt >> 2; // boundary tile index
  for (int it = wid; it <= nfull; it += 4) {
    int kt0 = it << 6;
    bool maskit = (it == nfull);
    f32x4 sacc[4];
#pragma unroll
    for (int s = 0; s < 4; s++) sacc[s] = (f32x4){0, 0, 0, 0};
#pragma unroll
    for (int s = 0; s < 4; s++) {
      const u16* krow = kp + (size_t)(kt0 + s * 16 + fr) * 128 + fo;
#pragma unroll
      for (int kc = 0; kc < 4; kc++) {
        bf16x8 kfr = *(const bf16x8*)(krow + kc * 32);
        sacc[s] = __builtin_amdgcn_mfma_f32_16x16x32_bf16(qfr[kc], kfr, sacc[s], 0, 0, 0);
      }
    }
    float fsc[4];
#pragma unroll
    for (int r = 0; r < 4; r++) {
      int qrow = qgb + r;
      float mx = -3e38f;
      if (maskit) {
#pragma unroll
        for (int s = 0; s < 4; s++) {
          int key = kt0 + s * 16 + fr;
          float v = (key <= qrow) ? sacc[s][r] : -3e38f;
          sacc[s][r] = v;
          mx = fmaxf(mx, v);
        }
      } else {
#pragma unroll
        for (int s = 0; s < 4; s++) mx = fmaxf(mx, sacc[s][r]);
      }
#pragma unroll
      for (int o = 1; o < 16; o <<= 1) mx = fmaxf(mx, __shfl_xor(mx, o, 64));
      float mn = fmaxf(mrow[r], mx);
      float f = __expf(mrow[r] - mn);
      mrow[r] = mn;
      float rs = 0.f;
#pragma unroll
      for (int s = 0; s < 4; s++) {
        float p = __expf(sacc[s][r] - mn);
        sacc[s][r] = p;
        rs += p;
      }
#pragma unroll
      for (int o = 1; o < 16; o <<= 1) rs += __shfl_xor(rs, o, 64);
      srow[r] = srow[r] * f + rs;
      fsc[r] = f;
    }
#pragma unroll
    for (int nd = 0; nd < 8; nd++)
#pragma unroll
      for (int r = 0; r < 4; r++) oacc[nd][r] *= fsc[r];
    // P -> LDS (u16 both sides, XOR-swizzled)
#pragma unroll
    for (int r = 0; r < 4; r++) {
      int row = lrb + r;
#pragma unroll
      for (int s = 0; s < 4; s++) {
        int a = row * 128 + (s * 16 + fr) * 2;
        plds[(a ^ ((row & 7) << 4)) >> 1] = f2bf(sacc[s][r]);
      }
    }
#pragma unroll
    for (int kc2 = 0; kc2 < 2; kc2++) {
      bf16x8 pa;
#pragma unroll
      for (int j = 0; j < 8; j++) {
        int a = fr * 128 + (kc2 * 32 + fo + j) * 2;
        u16 raw = plds[(a ^ ((fr & 7) << 4)) >> 1];
        union { u16 u; __bf16 b; } cv; cv.u = raw;
        pa[j] = cv.b;
      }
#pragma unroll
      for (int nd = 0; nd < 8; nd++) {
        const u16* vrow = vp + (size_t)(nd * 16 + fr) * TSEQ + kt0 + kc2 * 32 + fo;
        bf16x8 vfr = *(const bf16x8*)vrow;
        oacc[nd] = __builtin_amdgcn_mfma_f32_16x16x32_bf16(pa, vfr, oacc[nd], 0, 0, 0);
      }
    }
  }
  // ---- merge partials across the 4 waves ----
  __syncthreads(); // all waves done with plds (aliases OL)
#pragma unroll
  for (int r = 0; r < 4; r++) {
    int lr = lrb + r;
#pragma unroll
    for (int nd = 0; nd < 8; nd++)
      OL[(wid * 16 + lr) * 132 + nd * 16 + fr] = oacc[nd][r];
  }
  if (fr == 0) {
#pragma unroll
    for (int r = 0; r < 4; r++) {
      ML[wid * 16 + lrb + r] = mrow[r];
      LL[wid * 16 + lrb + r] = srow[r];
    }
  }
  __syncthreads();
  int b2 = bh >> 4, h2 = bh & 15;
  for (int idx = tid; idx < 2048; idx += 256) {
    int lr = idx >> 7, d = idx & 127;
    float m0 = ML[lr], m1 = ML[16 + lr], m2 = ML[32 + lr], m3 = ML[48 + lr];
    float mm = fmaxf(fmaxf(m0, m1), fmaxf(m2, m3));
    float e0 = __expf(m0 - mm), e1 = __expf(m1 - mm), e2 = __expf(m2 - mm), e3 = __expf(m3 - mm);
    float l = LL[lr] * e0 + LL[16 + lr] * e1 + LL[32 + lr] * e2 + LL[48 + lr] * e3;
    float o = OL[lr * 132 + d] * e0 + OL[(16 + lr) * 132 + d] * e1 +
              OL[(32 + lr) * 132 + d] * e2 + OL[(48 + lr) * 132 + d] * e3;
    y[((size_t)(b2 * TSEQ + q0 + lr)) * 2048 + h2 * 128 + d] = f2bf(o / l);
  }
}

extern "C" void kernel_launch(void* const* d_in, const int* in_sizes, int n_in,
                              void* d_out, int out_size, void* d_ws, size_t ws_size,
                              hipStream_t stream) {
  (void)in_sizes; (void)n_in; (void)out_size; (void)ws_size;
  const float* x      = (const float*)d_in[0];
  const float* ve     = (const float*)d_in[1];
  const float* cosp   = (const float*)d_in[2];
  const float* sinp   = (const float*)d_in[3];
  const float* w_dkv  = (const float*)d_in[4];
  const float* w_ukv  = (const float*)d_in[5];
  const float* w_kr   = (const float*)d_in[6];
  const float* w_dq   = (const float*)d_in[7];
  const float* w_q    = (const float*)d_in[8];
  const float* w_cp   = (const float*)d_in[9];
  const float* w_vg   = (const float*)d_in[10];
  float* out = (float*)d_out;   // reference output dtype is float32

  char* ws = (char*)d_ws;
  size_t off = 0;
  auto alloc = [&](size_t bytes) -> char* {
    char* p = ws + off;
    off += (bytes + 255) & ~(size_t)255;
    return p;
  };
  u16* xb     = (u16*)alloc(4096ull * 2048 * 2);
  u16* wdkvT  = (u16*)alloc(768ull * 2048 * 2);
  u16* wukvT  = (u16*)alloc(3072ull * 768 * 2);
  u16* wkrT   = (u16*)alloc(64ull * 2048 * 2);
  u16* wdqT   = (u16*)alloc(768ull * 2048 * 2);
  u16* wqT    = (u16*)alloc(2048ull * 768 * 2);
  u16* wcpT   = (u16*)alloc(2048ull * 2048 * 2);
  u16* ckv    = (u16*)alloc(4096ull * 768 * 2);
  u16* kvb    = (u16*)alloc(4096ull * 3072 * 2);
  u16* q1b    = (u16*)alloc(4096ull * 768 * 2);
  u16* qrawb  = (u16*)alloc(4096ull * 2048 * 2);
  u16* krb    = (u16*)alloc(4096ull * 64 * 2);
  float* gateb = (float*)alloc(4096ull * 16 * 4);
  u16* qfb    = (u16*)alloc(2ull * 16 * 2048 * 128 * 2);
  u16* kfb    = (u16*)alloc(2ull * 16 * 2048 * 128 * 2);
  u16* vtb    = (u16*)alloc(2ull * 16 * 128 * 2048 * 2);
  u16* yb = xb; // alias: x_bf dead after q1/k_rope/gate GEMMs

  // 1. conversions (DC padded 672 -> 768 so all big GEMMs are 128-tile-exact)
  k_conv_x<<<dim3(4096), dim3(256), 0, stream>>>(x, xb);
  k_tconv<<<dim3(64, 24), dim3(256), 0, stream>>>(w_dkv, wdkvT, 2048, 672, 2048);
  k_tconv<<<dim3(24, 96), dim3(256), 0, stream>>>(w_ukv, wukvT, 672, 3072, 768);
  k_tconv<<<dim3(64, 2),  dim3(256), 0, stream>>>(w_kr,  wkrT,  2048, 64, 2048);
  k_tconv<<<dim3(64, 24), dim3(256), 0, stream>>>(w_dq,  wdqT,  2048, 672, 2048);
  k_tconv<<<dim3(24, 64), dim3(256), 0, stream>>>(w_q,   wqT,   672, 2048, 768);
  k_tconv<<<dim3(64, 64), dim3(256), 0, stream>>>(w_cp,  wcpT,  2048, 2048, 2048);
  k_gate<<<dim3(256), dim3(256), 0, stream>>>(x, w_vg, gateb);

  // 2. projection GEMMs (128-tile + global_load_lds; kr stays on the 64-tile kernel)
  k_gemm128<u16><<<dim3(6, 32),  dim3(256), 0, stream>>>(xb,  wdkvT, ckv,   4096, 768, 2048);
  k_gemm128<u16><<<dim3(24, 32), dim3(256), 0, stream>>>(ckv, wukvT, kvb,   4096, 3072, 768);
  k_gemm_bt<u16><<<dim3(1, 64),  dim3(256), 0, stream>>>(xb,  wkrT,  krb,   4096, 64, 2048);
  k_gemm128<u16><<<dim3(6, 32),  dim3(256), 0, stream>>>(xb,  wdqT,  q1b,   4096, 768, 2048);
  k_gemm128<u16><<<dim3(16, 32), dim3(256), 0, stream>>>(q1b, wqT,   qrawb, 4096, 2048, 768);

  // 3. build q/k/v
  k_build_k<<<dim3(16384), dim3(256), 0, stream>>>(kvb, krb, cosp, sinp, kfb);
  k_build_q<<<dim3(16384), dim3(256), 0, stream>>>(qrawb, cosp, sinp, qfb);
  k_build_v<<<dim3(1024), dim3(256), 0, stream>>>(kvb, ve, gateb, vtb);

  // 4. attention -> y (aliases xb): 4096 blocks x 4 waves, key-split + merge, heavy-first
  k_attn<<<dim3(4096), dim3(256), 0, stream>>>(qfb, kfb, vtb, yb);

  // 5. output projection (f32 out -> d_out)
  k_gemm128<float><<<dim3(16, 32), dim3(256), 0, stream>>>(yb, wcpT, out, 4096, 2048, 2048);
}

// Round 8
// 493.101 us; speedup vs baseline: 1.2597x; 1.2597x over previous
//
#include <hip/hip_runtime.h>
#include <hip/hip_bf16.h>

typedef unsigned short u16;
typedef __bf16 bf16x8 __attribute__((ext_vector_type(8)));
typedef float f32x4 __attribute__((ext_vector_type(4)));
typedef u16 ushort8 __attribute__((ext_vector_type(8)));

#define TSEQ 2048
#define NHEAD 16

#define GLD16(gp, lp) __builtin_amdgcn_global_load_lds( \
    (__attribute__((address_space(1))) void*)(gp), \
    (__attribute__((address_space(3))) void*)(lp), 16, 0, 0)

static __device__ __forceinline__ float bf2f(u16 u) {
  unsigned int x = ((unsigned int)u) << 16;
  union { unsigned int i; float f; } c; c.i = x; return c.f;
}
static __device__ __forceinline__ u16 f2bf(float f) {
  union { float f; unsigned int i; } c; c.f = f;
  unsigned int x = c.i;
  unsigned int r = (x + 0x7FFFu + ((x >> 16) & 1u)) >> 16;
  return (u16)r;
}
static __device__ __forceinline__ void st_out(u16* p, float v) { *p = f2bf(v); }
static __device__ __forceinline__ void st_out(float* p, float v) { *p = v; }

// ---------------- convert x (f32 -> bf16), 8 elems/thread ----------------
__global__ __launch_bounds__(256) void k_conv_x(const float* __restrict__ x, u16* __restrict__ xb) {
  size_t i = ((size_t)blockIdx.x * 256 + threadIdx.x) * 8;
  float4 a = *(const float4*)(x + i);
  float4 b = *(const float4*)(x + i + 4);
  ushort8 o;
  o[0] = f2bf(a.x); o[1] = f2bf(a.y); o[2] = f2bf(a.z); o[3] = f2bf(a.w);
  o[4] = f2bf(b.x); o[5] = f2bf(b.y); o[6] = f2bf(b.z); o[7] = f2bf(b.w);
  *(ushort8*)(xb + i) = o;
}

// -------- transpose+convert weight: src f32 [R,Cc] -> dst bf16, dst[c][r]=src[r][c], zero-padded --------
__global__ __launch_bounds__(256) void k_tconv(const float* __restrict__ src, u16* __restrict__ dst,
                                               int R, int Cc, int Rpad) {
  __shared__ float sm[32][33];
  int tx = threadIdx.x & 31, ty = threadIdx.x >> 5;
  int r0 = blockIdx.x * 32, c0 = blockIdx.y * 32;
#pragma unroll
  for (int i = 0; i < 4; i++) {
    int r = r0 + ty + 8 * i;
    int c = c0 + tx;
    sm[ty + 8 * i][tx] = (r < R && c < Cc) ? src[(size_t)r * Cc + c] : 0.f;
  }
  __syncthreads();
#pragma unroll
  for (int i = 0; i < 4; i++) {
    int c = c0 + ty + 8 * i;
    dst[(size_t)c * Rpad + r0 + tx] = f2bf(sm[tx][ty + 8 * i]);
  }
}

// ---------------- gate = 2*sigmoid(x[:, :32] @ w_ve_gate) ----------------
__global__ __launch_bounds__(256) void k_gate(const float* __restrict__ x, const float* __restrict__ wg,
                                              float* __restrict__ gate) {
  int idx = blockIdx.x * 256 + threadIdx.x; // m*16 + h
  int m = idx >> 4, h = idx & 15;
  const float* xr = x + (size_t)m * 2048;
  float s = 0.f;
#pragma unroll
  for (int j = 0; j < 32; j++) s += xr[j] * wg[j * 16 + h];
  gate[idx] = 2.f / (1.f + __expf(-s));
}

// ---------------- 64x64 GEMM (kept for the tiny N=64 k_rope projection) ----------------
template <typename OT>
__global__ __launch_bounds__(256) void k_gemm_bt(const u16* __restrict__ A, const u16* __restrict__ BT,
                                                 OT* __restrict__ C, int M, int N, int K) {
  __shared__ __align__(16) u16 As[64][40];
  __shared__ __align__(16) u16 Bs[64][40];
  int t = threadIdx.x;
  int wid = t >> 6, lane = t & 63;
  int wr = (wid >> 1) * 32, wc = (wid & 1) * 32;
  int m0 = blockIdx.y * 64, n0 = blockIdx.x * 64;
  int lrow = t >> 2, lk = (t & 3) * 8;
  const u16* Ag = A + (size_t)(m0 + lrow) * K + lk;
  const u16* Bg = BT + (size_t)(n0 + lrow) * K + lk;
  f32x4 acc00 = {0,0,0,0}, acc01 = {0,0,0,0}, acc10 = {0,0,0,0}, acc11 = {0,0,0,0};
  int fr = lane & 15, fo = (lane >> 4) * 8;
  for (int k0 = 0; k0 < K; k0 += 32) {
    *(ushort8*)&As[lrow][lk] = *(const ushort8*)(Ag + k0);
    *(ushort8*)&Bs[lrow][lk] = *(const ushort8*)(Bg + k0);
    __syncthreads();
    bf16x8 a0 = *(const bf16x8*)&As[wr + fr][fo];
    bf16x8 a1 = *(const bf16x8*)&As[wr + 16 + fr][fo];
    bf16x8 b0 = *(const bf16x8*)&Bs[wc + fr][fo];
    bf16x8 b1 = *(const bf16x8*)&Bs[wc + 16 + fr][fo];
    acc00 = __builtin_amdgcn_mfma_f32_16x16x32_bf16(a0, b0, acc00, 0, 0, 0);
    acc01 = __builtin_amdgcn_mfma_f32_16x16x32_bf16(a0, b1, acc01, 0, 0, 0);
    acc10 = __builtin_amdgcn_mfma_f32_16x16x32_bf16(a1, b0, acc10, 0, 0, 0);
    acc11 = __builtin_amdgcn_mfma_f32_16x16x32_bf16(a1, b1, acc11, 0, 0, 0);
    __syncthreads();
  }
  int cr = (lane >> 4) * 4, cc = lane & 15;
#pragma unroll
  for (int r = 0; r < 4; r++) {
    size_t row0 = (size_t)(m0 + wr + cr + r);
    size_t row1 = row0 + 16;
    st_out(&C[row0 * N + n0 + wc + cc],      acc00[r]);
    st_out(&C[row0 * N + n0 + wc + 16 + cc], acc01[r]);
    st_out(&C[row1 * N + n0 + wc + cc],      acc10[r]);
    st_out(&C[row1 * N + n0 + wc + 16 + cc], acc11[r]);
  }
}

// ---------------- 128x128 GEMM, m97-style: linear LDS + global_load_lds w16, BK=32 ----------------
template <typename OT>
__global__ __launch_bounds__(256) void k_gemm128(const u16* __restrict__ A, const u16* __restrict__ BT,
                                                 OT* __restrict__ C, int M, int N, int K) {
  __shared__ __align__(16) u16 As[128 * 32];
  __shared__ __align__(16) u16 Bs[128 * 32];
  int t = threadIdx.x;
  int wid = t >> 6, lane = t & 63;
  int m0 = blockIdx.y * 128, n0 = blockIdx.x * 128;
  int c0 = wid * 2;
  int srow0 = c0 * 16 + (lane >> 2);
  int scol = (lane & 3) * 8;
  const u16* Ag0 = A + (size_t)(m0 + srow0) * K + scol;
  const u16* Ag1 = A + (size_t)(m0 + srow0 + 16) * K + scol;
  const u16* Bg0 = BT + (size_t)(n0 + srow0) * K + scol;
  const u16* Bg1 = BT + (size_t)(n0 + srow0 + 16) * K + scol;
  u16* Al0 = &As[c0 * 512];
  u16* Al1 = &As[c0 * 512 + 512];
  u16* Bl0 = &Bs[c0 * 512];
  u16* Bl1 = &Bs[c0 * 512 + 512];
  int wr = (wid >> 1) * 64, wc = (wid & 1) * 64;
  int fr = lane & 15, fo = (lane >> 4) * 8;
  f32x4 acc[4][4];
#pragma unroll
  for (int m = 0; m < 4; m++)
#pragma unroll
    for (int n = 0; n < 4; n++) acc[m][n] = (f32x4){0, 0, 0, 0};
  for (int k0 = 0; k0 < K; k0 += 32) {
    GLD16(Ag0 + k0, Al0);
    GLD16(Ag1 + k0, Al1);
    GLD16(Bg0 + k0, Bl0);
    GLD16(Bg1 + k0, Bl1);
    __syncthreads();
    bf16x8 af[4], bf[4];
#pragma unroll
    for (int m = 0; m < 4; m++) af[m] = *(const bf16x8*)&As[(wr + m * 16 + fr) * 32 + fo];
#pragma unroll
    for (int n = 0; n < 4; n++) bf[n] = *(const bf16x8*)&Bs[(wc + n * 16 + fr) * 32 + fo];
#pragma unroll
    for (int m = 0; m < 4; m++)
#pragma unroll
      for (int n = 0; n < 4; n++)
        acc[m][n] = __builtin_amdgcn_mfma_f32_16x16x32_bf16(af[m], bf[n], acc[m][n], 0, 0, 0);
    __syncthreads();
  }
  int cr = (lane >> 4) * 4, cc = lane & 15;
#pragma unroll
  for (int m = 0; m < 4; m++)
#pragma unroll
    for (int n = 0; n < 4; n++)
#pragma unroll
      for (int r = 0; r < 4; r++)
        st_out(&C[(size_t)(m0 + wr + m * 16 + cr + r) * N + n0 + wc + n * 16 + cc], acc[m][n][r]);
}

// ---------------- build K -> swizzled tile images ksw[bh][tile][16KB] ----------------
// tile image byte = (row*256 + d*2) ^ ((row&7)<<4), row = t within 64-tile, d = 0..127.
__global__ __launch_bounds__(256) void k_build_k(const u16* __restrict__ kv, const u16* __restrict__ kr,
                                                 const float* __restrict__ cosp, const float* __restrict__ sinp,
                                                 u16* __restrict__ ksw) {
  __shared__ __align__(16) u16 sm[8192];
  int tid = threadIdx.x, wid = tid >> 6, lane = tid & 63;
  int bh = blockIdx.x >> 5, tile = blockIdx.x & 31;
  int b = bh >> 4, h = bh & 15;
  int d0 = lane * 2;
  for (int rr = 0; rr < 16; rr++) {
    int row = wid * 16 + rr;
    int t = tile * 64 + row;
    int m = b * TSEQ + t;
    float v[2];
#pragma unroll
    for (int e = 0; e < 2; e++) {
      int d = d0 + e;
      float val;
      if (d < 64) {
        val = bf2f(kv[(size_t)m * 3072 + h * 192 + d]);
      } else {
        int dd = d - 64, i = dd & 31;
        float c = cosp[m * 32 + i], s = sinp[m * 32 + i];
        float x1 = bf2f(kr[(size_t)m * 64 + i]), x2 = bf2f(kr[(size_t)m * 64 + 32 + i]);
        val = (dd < 32) ? (x1 * c + x2 * s) : (x2 * c - x1 * s);
      }
      v[e] = val;
    }
    float ss = v[0] * v[0] + v[1] * v[1];
#pragma unroll
    for (int o = 1; o < 64; o <<= 1) ss += __shfl_xor(ss, o, 64);
    float rms = rsqrtf(ss * (1.f / 128.f) + 1.1920929e-7f);
    int a = (row * 256 + d0 * 2) ^ ((row & 7) << 4);
    sm[a >> 1] = f2bf(v[0] * rms);
    sm[(a >> 1) + 1] = f2bf(v[1] * rms);
  }
  __syncthreads();
  u16* dst = ksw + ((size_t)(bh * 32 + tile)) * 8192 + tid * 32;
  const u16* src = sm + tid * 32;
#pragma unroll
  for (int j = 0; j < 4; j++)
    *(ushort8*)(dst + j * 8) = *(const ushort8*)(src + j * 8);
}

// ---------------- build Q: concat(q_nope, rope(q_rope)), rmsnorm * 1/sqrt(128) ----------------
__global__ __launch_bounds__(256) void k_build_q(const u16* __restrict__ qr,
                                                 const float* __restrict__ cosp, const float* __restrict__ sinp,
                                                 u16* __restrict__ qf) {
  int wid = threadIdx.x >> 6, lane = threadIdx.x & 63;
  int idx = blockIdx.x * 4 + wid; // m*16 + h
  int m = idx >> 4, h = idx & 15;
  size_t bin = (size_t)m * 2048 + h * 128;
  int d0 = lane * 2;
  float v[2];
#pragma unroll
  for (int e = 0; e < 2; e++) {
    int d = d0 + e;
    float val;
    if (d < 64) {
      val = bf2f(qr[bin + d]);
    } else {
      int dd = d - 64, i = dd & 31;
      float c = cosp[m * 32 + i], s = sinp[m * 32 + i];
      float x1 = bf2f(qr[bin + 64 + i]), x2 = bf2f(qr[bin + 96 + i]);
      val = (dd < 32) ? (x1 * c + x2 * s) : (x2 * c - x1 * s);
    }
    v[e] = val;
  }
  float ss = v[0] * v[0] + v[1] * v[1];
#pragma unroll
  for (int o = 1; o < 64; o <<= 1) ss += __shfl_xor(ss, o, 64);
  float rms = rsqrtf(ss * (1.f / 128.f) + 1.1920929e-7f) * 0.08838834764831845f;
  int b = m >> 11, tt = m & 2047;
  size_t base = ((size_t)(b * NHEAD + h) * TSEQ + tt) * 128 + d0;
  qf[base] = f2bf(v[0] * rms);
  qf[base + 1] = f2bf(v[1] * rms);
}

// ---------------- build V -> swizzled tile images vsw[bh][tile][16KB] ----------------
// tile image byte = (d*128 + k*2) ^ ((d&7)<<4), d = 0..127, k = t within 64-tile.
// sm is built with exactly this swizzle, so the output phase is a straight memcpy.
__global__ __launch_bounds__(256) void k_build_v(const u16* __restrict__ kv, const float* __restrict__ ve,
                                                 const float* __restrict__ gate, u16* __restrict__ vsw) {
  __shared__ __align__(16) char sm[128 * 128];
  int bh = blockIdx.x >> 5, tile = blockIdx.x & 31;
  int t0 = tile * 64;
  int b = bh >> 4, h = bh & 15;
  int tt = threadIdx.x >> 2, dp = (threadIdx.x & 3) * 32;
  int m = b * TSEQ + t0 + tt;
  float g = gate[m * 16 + h];
  const u16* kvp = kv + (size_t)m * 3072 + h * 192 + 64 + dp;
  const float* vep = ve + (size_t)m * 2048 + h * 128 + dp;
  ushort8 kvv[4];
  float4 vev[8];
#pragma unroll
  for (int u = 0; u < 4; u++) kvv[u] = *(const ushort8*)(kvp + u * 8);
#pragma unroll
  for (int u = 0; u < 8; u++) vev[u] = *(const float4*)(vep + u * 4);
#pragma unroll
  for (int j = 0; j < 32; j++) {
    float vvf = ((const float*)&vev[j >> 2])[j & 3];
    float v = bf2f(kvv[j >> 3][j & 7]) + g * vvf;
    int row = dp + j;
    int a = row * 128 + tt * 2;
    *(u16*)(sm + (a ^ ((row & 7) << 4))) = f2bf(v);
  }
  __syncthreads();
  u16* dst = vsw + ((size_t)(bh * 32 + tile)) * 8192 + threadIdx.x * 32;
  const u16* src = (const u16*)sm + threadIdx.x * 32;
#pragma unroll
  for (int j = 0; j < 4; j++)
    *(ushort8*)(dst + j * 8) = *(const ushort8*)(src + j * 8);
}

// ---------------- flash attention: 64-row Q-block, 4 waves, K/V double-buffered in LDS ----------------
// ksw/vsw hold pre-swizzled 16KB tile images; global_load_lds stages them linearly.
__global__ __launch_bounds__(256) void k_attn(const u16* __restrict__ qf, const u16* __restrict__ ksw,
                                              const u16* __restrict__ vsw, u16* __restrict__ y) {
  __shared__ __align__(16) u16 kvbuf[2][2][8192]; // [buf][K=0/V=1][16KB]
  __shared__ u16 plds_all[4][1024];
  int tid = threadIdx.x, wid = tid >> 6, lane = tid & 63;
  // bijective XCD-chunked task map: each XCD gets 4 heads (2MB KV -> L2-resident)
  int task = (blockIdx.x & 7) * 128 + (blockIdx.x >> 3);
  int bh = task >> 5;
  int qb = 31 - (task & 31);            // heavy-first within head
  int nt = qb + 1;
  int q0 = qb * 64 + wid * 16;
  const u16* qp = qf + (size_t)bh * TSEQ * 128;
  const u16* kswb = ksw + (size_t)bh * 32 * 8192;
  const u16* vswb = vsw + (size_t)bh * 32 * 8192;
  int fr = lane & 15, fo = (lane >> 4) * 8;
  bf16x8 qfr[4];
#pragma unroll
  for (int kc = 0; kc < 4; kc++)
    qfr[kc] = *(const bf16x8*)(qp + (size_t)(q0 + fr) * 128 + kc * 32 + fo);
  f32x4 oacc[8];
#pragma unroll
  for (int nd = 0; nd < 8; nd++) oacc[nd] = (f32x4){0, 0, 0, 0};
  float mrow[4] = {-1e30f, -1e30f, -1e30f, -1e30f};
  float srow[4] = {0, 0, 0, 0};
  int qgb = q0 + (lane >> 4) * 4;
  int lrb = (lane >> 4) * 4;
  u16* plds = plds_all[wid];
  int chunk = wid * 4; // this wave stages chunks chunk..chunk+3 (1KB each) of K and V
  // stage tile 0 into buf 0
#pragma unroll
  for (int j = 0; j < 4; j++) {
    GLD16(kswb + (chunk + j) * 512 + lane * 8, &kvbuf[0][0][(chunk + j) * 512]);
    GLD16(vswb + (chunk + j) * 512 + lane * 8, &kvbuf[0][1][(chunk + j) * 512]);
  }
  __syncthreads();
  for (int it = 0; it < nt; it++) {
    int cur = it & 1;
    if (it + 1 < nt) {
      const u16* kt = kswb + (size_t)(it + 1) * 8192;
      const u16* vt = vswb + (size_t)(it + 1) * 8192;
#pragma unroll
      for (int j = 0; j < 4; j++) {
        GLD16(kt + (chunk + j) * 512 + lane * 8, &kvbuf[cur ^ 1][0][(chunk + j) * 512]);
        GLD16(vt + (chunk + j) * 512 + lane * 8, &kvbuf[cur ^ 1][1][(chunk + j) * 512]);
      }
    }
    const char* Kt = (const char*)kvbuf[cur][0];
    const char* Vt = (const char*)kvbuf[cur][1];
    int kt0 = it * 64;
    bool maskit = (it == nt - 1);
    f32x4 sacc[4];
#pragma unroll
    for (int s = 0; s < 4; s++) sacc[s] = (f32x4){0, 0, 0, 0};
#pragma unroll
    for (int s = 0; s < 4; s++) {
      int row = s * 16 + fr;
      int abase = (row * 256) ^ ((row & 7) << 4); // col-xor only affects bits<8 of col part
#pragma unroll
      for (int kc = 0; kc < 4; kc++) {
        int a = (row * 256 + (kc * 32 + fo) * 2) ^ ((row & 7) << 4);
        bf16x8 kfr = *(const bf16x8*)(Kt + a);
        sacc[s] = __builtin_amdgcn_mfma_f32_16x16x32_bf16(qfr[kc], kfr, sacc[s], 0, 0, 0);
      }
      (void)abase;
    }
    float fsc[4];
#pragma unroll
    for (int r = 0; r < 4; r++) {
      int qrow = qgb + r;
      float mx = -3e38f;
      if (maskit) {
#pragma unroll
        for (int s = 0; s < 4; s++) {
          int key = kt0 + s * 16 + fr;
          float v = (key <= qrow) ? sacc[s][r] : -3e38f;
          sacc[s][r] = v;
          mx = fmaxf(mx, v);
        }
      } else {
#pragma unroll
        for (int s = 0; s < 4; s++) mx = fmaxf(mx, sacc[s][r]);
      }
#pragma unroll
      for (int o = 1; o < 16; o <<= 1) mx = fmaxf(mx, __shfl_xor(mx, o, 64));
      float mn = fmaxf(mrow[r], mx);
      float f = __expf(mrow[r] - mn);
      mrow[r] = mn;
      float rs = 0.f;
#pragma unroll
      for (int s = 0; s < 4; s++) {
        float p = __expf(sacc[s][r] - mn);
        sacc[s][r] = p;
        rs += p;
      }
#pragma unroll
      for (int o = 1; o < 16; o <<= 1) rs += __shfl_xor(rs, o, 64);
      srow[r] = srow[r] * f + rs;
      fsc[r] = f;
    }
#pragma unroll
    for (int nd = 0; nd < 8; nd++)
#pragma unroll
      for (int r = 0; r < 4; r++) oacc[nd][r] *= fsc[r];
    // P -> LDS (u16 both sides, XOR-swizzled)
#pragma unroll
    for (int r = 0; r < 4; r++) {
      int row = lrb + r;
#pragma unroll
      for (int s = 0; s < 4; s++) {
        int a = row * 128 + (s * 16 + fr) * 2;
        plds[(a ^ ((row & 7) << 4)) >> 1] = f2bf(sacc[s][r]);
      }
    }
#pragma unroll
    for (int kc2 = 0; kc2 < 2; kc2++) {
      bf16x8 pa;
#pragma unroll
      for (int j = 0; j < 8; j++) {
        int a = fr * 128 + (kc2 * 32 + fo + j) * 2;
        u16 raw = plds[(a ^ ((fr & 7) << 4)) >> 1];
        union { u16 u; __bf16 b; } cv; cv.u = raw;
        pa[j] = cv.b;
      }
#pragma unroll
      for (int nd = 0; nd < 8; nd++) {
        int vrow = nd * 16 + fr;
        int a = (vrow * 128 + (kc2 * 32 + fo) * 2) ^ ((vrow & 7) << 4);
        bf16x8 vfr = *(const bf16x8*)(Vt + a);
        oacc[nd] = __builtin_amdgcn_mfma_f32_16x16x32_bf16(pa, vfr, oacc[nd], 0, 0, 0);
      }
    }
    __syncthreads(); // drains this wave's GLD queue; next buffer ready, cur free for restage
  }
  int b2 = bh >> 4, h2 = bh & 15;
  float inv[4];
#pragma unroll
  for (int r = 0; r < 4; r++) inv[r] = 1.f / srow[r];
#pragma unroll
  for (int nd = 0; nd < 8; nd++) {
#pragma unroll
    for (int r = 0; r < 4; r++) {
      int qrow = qgb + r;
      size_t offo = ((size_t)(b2 * TSEQ + qrow)) * 2048 + h2 * 128 + nd * 16 + fr;
      y[offo] = f2bf(oacc[nd][r] * inv[r]);
    }
  }
}

extern "C" void kernel_launch(void* const* d_in, const int* in_sizes, int n_in,
                              void* d_out, int out_size, void* d_ws, size_t ws_size,
                              hipStream_t stream) {
  (void)in_sizes; (void)n_in; (void)out_size; (void)ws_size;
  const float* x      = (const float*)d_in[0];
  const float* ve     = (const float*)d_in[1];
  const float* cosp   = (const float*)d_in[2];
  const float* sinp   = (const float*)d_in[3];
  const float* w_dkv  = (const float*)d_in[4];
  const float* w_ukv  = (const float*)d_in[5];
  const float* w_kr   = (const float*)d_in[6];
  const float* w_dq   = (const float*)d_in[7];
  const float* w_q    = (const float*)d_in[8];
  const float* w_cp   = (const float*)d_in[9];
  const float* w_vg   = (const float*)d_in[10];
  float* out = (float*)d_out;   // reference output dtype is float32

  char* ws = (char*)d_ws;
  size_t off = 0;
  auto alloc = [&](size_t bytes) -> char* {
    char* p = ws + off;
    off += (bytes + 255) & ~(size_t)255;
    return p;
  };
  u16* xb     = (u16*)alloc(4096ull * 2048 * 2);
  u16* wdkvT  = (u16*)alloc(768ull * 2048 * 2);
  u16* wukvT  = (u16*)alloc(3072ull * 768 * 2);
  u16* wkrT   = (u16*)alloc(64ull * 2048 * 2);
  u16* wdqT   = (u16*)alloc(768ull * 2048 * 2);
  u16* wqT    = (u16*)alloc(2048ull * 768 * 2);
  u16* wcpT   = (u16*)alloc(2048ull * 2048 * 2);
  u16* ckv    = (u16*)alloc(4096ull * 768 * 2);
  u16* kvb    = (u16*)alloc(4096ull * 3072 * 2);
  u16* q1b    = (u16*)alloc(4096ull * 768 * 2);
  u16* qrawb  = (u16*)alloc(4096ull * 2048 * 2);
  u16* krb    = (u16*)alloc(4096ull * 64 * 2);
  float* gateb = (float*)alloc(4096ull * 16 * 4);
  u16* qfb    = (u16*)alloc(2ull * 16 * 2048 * 128 * 2);
  u16* kswb   = (u16*)alloc(32ull * 32 * 8192 * 2);  // swizzled K tiles
  u16* vswb   = (u16*)alloc(32ull * 32 * 8192 * 2);  // swizzled V tiles
  u16* yb = xb; // alias: x_bf dead after q1/k_rope/gate GEMMs

  // 1. conversions (DC padded 672 -> 768 so all big GEMMs are 128-tile-exact)
  k_conv_x<<<dim3(4096), dim3(256), 0, stream>>>(x, xb);
  k_tconv<<<dim3(64, 24), dim3(256), 0, stream>>>(w_dkv, wdkvT, 2048, 672, 2048);
  k_tconv<<<dim3(24, 96), dim3(256), 0, stream>>>(w_ukv, wukvT, 672, 3072, 768);
  k_tconv<<<dim3(64, 2),  dim3(256), 0, stream>>>(w_kr,  wkrT,  2048, 64, 2048);
  k_tconv<<<dim3(64, 24), dim3(256), 0, stream>>>(w_dq,  wdqT,  2048, 672, 2048);
  k_tconv<<<dim3(24, 64), dim3(256), 0, stream>>>(w_q,   wqT,   672, 2048, 768);
  k_tconv<<<dim3(64, 64), dim3(256), 0, stream>>>(w_cp,  wcpT,  2048, 2048, 2048);
  k_gate<<<dim3(256), dim3(256), 0, stream>>>(x, w_vg, gateb);

  // 2. projection GEMMs
  k_gemm128<u16><<<dim3(6, 32),  dim3(256), 0, stream>>>(xb,  wdkvT, ckv,   4096, 768, 2048);
  k_gemm128<u16><<<dim3(24, 32), dim3(256), 0, stream>>>(ckv, wukvT, kvb,   4096, 3072, 768);
  k_gemm_bt<u16><<<dim3(1, 64),  dim3(256), 0, stream>>>(xb,  wkrT,  krb,   4096, 64, 2048);
  k_gemm128<u16><<<dim3(6, 32),  dim3(256), 0, stream>>>(xb,  wdqT,  q1b,   4096, 768, 2048);
  k_gemm128<u16><<<dim3(16, 32), dim3(256), 0, stream>>>(q1b, wqT,   qrawb, 4096, 2048, 768);

  // 3. build q/k/v (k and v emit pre-swizzled 16KB tile images)
  k_build_k<<<dim3(1024), dim3(256), 0, stream>>>(kvb, krb, cosp, sinp, kswb);
  k_build_q<<<dim3(16384), dim3(256), 0, stream>>>(qrawb, cosp, sinp, qfb);
  k_build_v<<<dim3(1024), dim3(256), 0, stream>>>(kvb, ve, gateb, vswb);

  // 4. attention -> y (aliases xb): 1024 blocks x 4 waves, staged K/V, XCD-chunked
  k_attn<<<dim3(1024), dim3(256), 0, stream>>>(qfb, kswb, vswb, yb);

  // 5. output projection (f32 out -> d_out)
  k_gemm128<float><<<dim3(16, 32), dim3(256), 0, stream>>>(yb, wcpT, out, 4096, 2048, 2048);
}

// Round 9
// 435.028 us; speedup vs baseline: 1.4279x; 1.1335x over previous
//
#include <hip/hip_runtime.h>
#include <hip/hip_bf16.h>

typedef unsigned short u16;
typedef unsigned int u32;
typedef __bf16 bf16x8 __attribute__((ext_vector_type(8)));
typedef float f32x4 __attribute__((ext_vector_type(4)));
typedef u16 ushort8 __attribute__((ext_vector_type(8)));

#define TSEQ 2048
#define NHEAD 16

#define GLD16(gp, lp) __builtin_amdgcn_global_load_lds( \
    (__attribute__((address_space(1))) void*)(gp), \
    (__attribute__((address_space(3))) void*)(lp), 16, 0, 0)

static __device__ __forceinline__ float bf2f(u16 u) {
  unsigned int x = ((unsigned int)u) << 16;
  union { unsigned int i; float f; } c; c.i = x; return c.f;
}
static __device__ __forceinline__ u16 f2bf(float f) {
  union { float f; unsigned int i; } c; c.f = f;
  unsigned int x = c.i;
  unsigned int r = (x + 0x7FFFu + ((x >> 16) & 1u)) >> 16;
  return (u16)r;
}
static __device__ __forceinline__ void st_out(u16* p, float v) { *p = f2bf(v); }
static __device__ __forceinline__ void st_out(float* p, float v) { *p = v; }
static __device__ __forceinline__ u32 cvtpk(float lo, float hi) {
  u32 w;
  asm("v_cvt_pk_bf16_f32 %0, %1, %2" : "=v"(w) : "v"(lo), "v"(hi));
  return w;
}

// ---------------- convert x (f32 -> bf16), 8 elems/thread ----------------
__global__ __launch_bounds__(256) void k_conv_x(const float* __restrict__ x, u16* __restrict__ xb) {
  size_t i = ((size_t)blockIdx.x * 256 + threadIdx.x) * 8;
  float4 a = *(const float4*)(x + i);
  float4 b = *(const float4*)(x + i + 4);
  ushort8 o;
  o[0] = f2bf(a.x); o[1] = f2bf(a.y); o[2] = f2bf(a.z); o[3] = f2bf(a.w);
  o[4] = f2bf(b.x); o[5] = f2bf(b.y); o[6] = f2bf(b.z); o[7] = f2bf(b.w);
  *(ushort8*)(xb + i) = o;
}

// -------- transpose+convert weight: src f32 [R,Cc] -> dst bf16, dst[c][r]=src[r][c], zero-padded --------
__global__ __launch_bounds__(256) void k_tconv(const float* __restrict__ src, u16* __restrict__ dst,
                                               int R, int Cc, int Rpad) {
  __shared__ float sm[32][33];
  int tx = threadIdx.x & 31, ty = threadIdx.x >> 5;
  int r0 = blockIdx.x * 32, c0 = blockIdx.y * 32;
#pragma unroll
  for (int i = 0; i < 4; i++) {
    int r = r0 + ty + 8 * i;
    int c = c0 + tx;
    sm[ty + 8 * i][tx] = (r < R && c < Cc) ? src[(size_t)r * Cc + c] : 0.f;
  }
  __syncthreads();
#pragma unroll
  for (int i = 0; i < 4; i++) {
    int c = c0 + ty + 8 * i;
    dst[(size_t)c * Rpad + r0 + tx] = f2bf(sm[tx][ty + 8 * i]);
  }
}

// ---------------- gate = 2*sigmoid(x[:, :32] @ w_ve_gate) ----------------
__global__ __launch_bounds__(256) void k_gate(const float* __restrict__ x, const float* __restrict__ wg,
                                              float* __restrict__ gate) {
  int idx = blockIdx.x * 256 + threadIdx.x; // m*16 + h
  int m = idx >> 4, h = idx & 15;
  const float* xr = x + (size_t)m * 2048;
  float s = 0.f;
#pragma unroll
  for (int j = 0; j < 32; j++) s += xr[j] * wg[j * 16 + h];
  gate[idx] = 2.f / (1.f + __expf(-s));
}

// ---------------- 64x64 GEMM (kept for the tiny N=64 k_rope projection) ----------------
template <typename OT>
__global__ __launch_bounds__(256) void k_gemm_bt(const u16* __restrict__ A, const u16* __restrict__ BT,
                                                 OT* __restrict__ C, int M, int N, int K) {
  __shared__ __align__(16) u16 As[64][40];
  __shared__ __align__(16) u16 Bs[64][40];
  int t = threadIdx.x;
  int wid = t >> 6, lane = t & 63;
  int wr = (wid >> 1) * 32, wc = (wid & 1) * 32;
  int m0 = blockIdx.y * 64, n0 = blockIdx.x * 64;
  int lrow = t >> 2, lk = (t & 3) * 8;
  const u16* Ag = A + (size_t)(m0 + lrow) * K + lk;
  const u16* Bg = BT + (size_t)(n0 + lrow) * K + lk;
  f32x4 acc00 = {0,0,0,0}, acc01 = {0,0,0,0}, acc10 = {0,0,0,0}, acc11 = {0,0,0,0};
  int fr = lane & 15, fo = (lane >> 4) * 8;
  for (int k0 = 0; k0 < K; k0 += 32) {
    *(ushort8*)&As[lrow][lk] = *(const ushort8*)(Ag + k0);
    *(ushort8*)&Bs[lrow][lk] = *(const ushort8*)(Bg + k0);
    __syncthreads();
    bf16x8 a0 = *(const bf16x8*)&As[wr + fr][fo];
    bf16x8 a1 = *(const bf16x8*)&As[wr + 16 + fr][fo];
    bf16x8 b0 = *(const bf16x8*)&Bs[wc + fr][fo];
    bf16x8 b1 = *(const bf16x8*)&Bs[wc + 16 + fr][fo];
    acc00 = __builtin_amdgcn_mfma_f32_16x16x32_bf16(a0, b0, acc00, 0, 0, 0);
    acc01 = __builtin_amdgcn_mfma_f32_16x16x32_bf16(a0, b1, acc01, 0, 0, 0);
    acc10 = __builtin_amdgcn_mfma_f32_16x16x32_bf16(a1, b0, acc10, 0, 0, 0);
    acc11 = __builtin_amdgcn_mfma_f32_16x16x32_bf16(a1, b1, acc11, 0, 0, 0);
    __syncthreads();
  }
  int cr = (lane >> 4) * 4, cc = lane & 15;
#pragma unroll
  for (int r = 0; r < 4; r++) {
    size_t row0 = (size_t)(m0 + wr + cr + r);
    size_t row1 = row0 + 16;
    st_out(&C[row0 * N + n0 + wc + cc],      acc00[r]);
    st_out(&C[row0 * N + n0 + wc + 16 + cc], acc01[r]);
    st_out(&C[row1 * N + n0 + wc + cc],      acc10[r]);
    st_out(&C[row1 * N + n0 + wc + 16 + cc], acc11[r]);
  }
}

// ---------------- 128x128 GEMM, m97-style: linear LDS + global_load_lds w16, BK=32 ----------------
template <typename OT>
__global__ __launch_bounds__(256) void k_gemm128(const u16* __restrict__ A, const u16* __restrict__ BT,
                                                 OT* __restrict__ C, int M, int N, int K) {
  __shared__ __align__(16) u16 As[128 * 32];
  __shared__ __align__(16) u16 Bs[128 * 32];
  int t = threadIdx.x;
  int wid = t >> 6, lane = t & 63;
  int m0 = blockIdx.y * 128, n0 = blockIdx.x * 128;
  int c0 = wid * 2;
  int srow0 = c0 * 16 + (lane >> 2);
  int scol = (lane & 3) * 8;
  const u16* Ag0 = A + (size_t)(m0 + srow0) * K + scol;
  const u16* Ag1 = A + (size_t)(m0 + srow0 + 16) * K + scol;
  const u16* Bg0 = BT + (size_t)(n0 + srow0) * K + scol;
  const u16* Bg1 = BT + (size_t)(n0 + srow0 + 16) * K + scol;
  u16* Al0 = &As[c0 * 512];
  u16* Al1 = &As[c0 * 512 + 512];
  u16* Bl0 = &Bs[c0 * 512];
  u16* Bl1 = &Bs[c0 * 512 + 512];
  int wr = (wid >> 1) * 64, wc = (wid & 1) * 64;
  int fr = lane & 15, fo = (lane >> 4) * 8;
  f32x4 acc[4][4];
#pragma unroll
  for (int m = 0; m < 4; m++)
#pragma unroll
    for (int n = 0; n < 4; n++) acc[m][n] = (f32x4){0, 0, 0, 0};
  for (int k0 = 0; k0 < K; k0 += 32) {
    GLD16(Ag0 + k0, Al0);
    GLD16(Ag1 + k0, Al1);
    GLD16(Bg0 + k0, Bl0);
    GLD16(Bg1 + k0, Bl1);
    __syncthreads();
    bf16x8 af[4], bf[4];
#pragma unroll
    for (int m = 0; m < 4; m++) af[m] = *(const bf16x8*)&As[(wr + m * 16 + fr) * 32 + fo];
#pragma unroll
    for (int n = 0; n < 4; n++) bf[n] = *(const bf16x8*)&Bs[(wc + n * 16 + fr) * 32 + fo];
#pragma unroll
    for (int m = 0; m < 4; m++)
#pragma unroll
      for (int n = 0; n < 4; n++)
        acc[m][n] = __builtin_amdgcn_mfma_f32_16x16x32_bf16(af[m], bf[n], acc[m][n], 0, 0, 0);
    __syncthreads();
  }
  int cr = (lane >> 4) * 4, cc = lane & 15;
#pragma unroll
  for (int m = 0; m < 4; m++)
#pragma unroll
    for (int n = 0; n < 4; n++)
#pragma unroll
      for (int r = 0; r < 4; r++)
        st_out(&C[(size_t)(m0 + wr + m * 16 + cr + r) * N + n0 + wc + n * 16 + cc], acc[m][n][r]);
}

// ---------------- build K -> swizzled tile images ksw[bh][tile][16KB] ----------------
__global__ __launch_bounds__(256) void k_build_k(const u16* __restrict__ kv, const u16* __restrict__ kr,
                                                 const float* __restrict__ cosp, const float* __restrict__ sinp,
                                                 u16* __restrict__ ksw) {
  __shared__ __align__(16) u16 sm[8192];
  int tid = threadIdx.x, wid = tid >> 6, lane = tid & 63;
  int bh = blockIdx.x >> 5, tile = blockIdx.x & 31;
  int b = bh >> 4, h = bh & 15;
  int d0 = lane * 2;
  for (int rr = 0; rr < 16; rr++) {
    int row = wid * 16 + rr;
    int t = tile * 64 + row;
    int m = b * TSEQ + t;
    float v[2];
#pragma unroll
    for (int e = 0; e < 2; e++) {
      int d = d0 + e;
      float val;
      if (d < 64) {
        val = bf2f(kv[(size_t)m * 3072 + h * 192 + d]);
      } else {
        int dd = d - 64, i = dd & 31;
        float c = cosp[m * 32 + i], s = sinp[m * 32 + i];
        float x1 = bf2f(kr[(size_t)m * 64 + i]), x2 = bf2f(kr[(size_t)m * 64 + 32 + i]);
        val = (dd < 32) ? (x1 * c + x2 * s) : (x2 * c - x1 * s);
      }
      v[e] = val;
    }
    float ss = v[0] * v[0] + v[1] * v[1];
#pragma unroll
    for (int o = 1; o < 64; o <<= 1) ss += __shfl_xor(ss, o, 64);
    float rms = rsqrtf(ss * (1.f / 128.f) + 1.1920929e-7f);
    int a = (row * 256 + d0 * 2) ^ ((row & 7) << 4);
    sm[a >> 1] = f2bf(v[0] * rms);
    sm[(a >> 1) + 1] = f2bf(v[1] * rms);
  }
  __syncthreads();
  u16* dst = ksw + ((size_t)(bh * 32 + tile)) * 8192 + tid * 32;
  const u16* src = sm + tid * 32;
#pragma unroll
  for (int j = 0; j < 4; j++)
    *(ushort8*)(dst + j * 8) = *(const ushort8*)(src + j * 8);
}

// ---------------- build Q: concat(q_nope, rope(q_rope)), rmsnorm * 1/sqrt(128) ----------------
__global__ __launch_bounds__(256) void k_build_q(const u16* __restrict__ qr,
                                                 const float* __restrict__ cosp, const float* __restrict__ sinp,
                                                 u16* __restrict__ qf) {
  int wid = threadIdx.x >> 6, lane = threadIdx.x & 63;
  int idx = blockIdx.x * 4 + wid; // m*16 + h
  int m = idx >> 4, h = idx & 15;
  size_t bin = (size_t)m * 2048 + h * 128;
  int d0 = lane * 2;
  float v[2];
#pragma unroll
  for (int e = 0; e < 2; e++) {
    int d = d0 + e;
    float val;
    if (d < 64) {
      val = bf2f(qr[bin + d]);
    } else {
      int dd = d - 64, i = dd & 31;
      float c = cosp[m * 32 + i], s = sinp[m * 32 + i];
      float x1 = bf2f(qr[bin + 64 + i]), x2 = bf2f(qr[bin + 96 + i]);
      val = (dd < 32) ? (x1 * c + x2 * s) : (x2 * c - x1 * s);
    }
    v[e] = val;
  }
  float ss = v[0] * v[0] + v[1] * v[1];
#pragma unroll
  for (int o = 1; o < 64; o <<= 1) ss += __shfl_xor(ss, o, 64);
  float rms = rsqrtf(ss * (1.f / 128.f) + 1.1920929e-7f) * 0.08838834764831845f;
  int b = m >> 11, tt = m & 2047;
  size_t base = ((size_t)(b * NHEAD + h) * TSEQ + tt) * 128 + d0;
  qf[base] = f2bf(v[0] * rms);
  qf[base + 1] = f2bf(v[1] * rms);
}

// ---------------- build V -> swizzled tile images vsw[bh][tile][16KB] ----------------
__global__ __launch_bounds__(256) void k_build_v(const u16* __restrict__ kv, const float* __restrict__ ve,
                                                 const float* __restrict__ gate, u16* __restrict__ vsw) {
  __shared__ __align__(16) char sm[128 * 128];
  int bh = blockIdx.x >> 5, tile = blockIdx.x & 31;
  int t0 = tile * 64;
  int b = bh >> 4, h = bh & 15;
  int tt = threadIdx.x >> 2, dp = (threadIdx.x & 3) * 32;
  int m = b * TSEQ + t0 + tt;
  float g = gate[m * 16 + h];
  const u16* kvp = kv + (size_t)m * 3072 + h * 192 + 64 + dp;
  const float* vep = ve + (size_t)m * 2048 + h * 128 + dp;
  ushort8 kvv[4];
  float4 vev[8];
#pragma unroll
  for (int u = 0; u < 4; u++) kvv[u] = *(const ushort8*)(kvp + u * 8);
#pragma unroll
  for (int u = 0; u < 8; u++) vev[u] = *(const float4*)(vep + u * 4);
#pragma unroll
  for (int j = 0; j < 32; j++) {
    float vvf = ((const float*)&vev[j >> 2])[j & 3];
    float v = bf2f(kvv[j >> 3][j & 7]) + g * vvf;
    int row = dp + j;
    int a = row * 128 + tt * 2;
    *(u16*)(sm + (a ^ ((row & 7) << 4))) = f2bf(v);
  }
  __syncthreads();
  u16* dst = vsw + ((size_t)(bh * 32 + tile)) * 8192 + threadIdx.x * 32;
  const u16* src = (const u16*)sm + threadIdx.x * 32;
#pragma unroll
  for (int j = 0; j < 4; j++)
    *(ushort8*)(dst + j * 8) = *(const ushort8*)(src + j * 8);
}

// ---------------- flash attention: swapped QK^T (lane-local softmax), staged K/V ----------------
// Per lane: g = lane>>4, c = lane&15. sacc[s][r] = S[k = s*16+g*4+r][q = c] (swapped mfma(K,Q)).
// All 16 S-values in a lane belong to q-row c -> max/sum are lane trees + 2 shfl_xor.
// P packed via v_cvt_pk_bf16_f32 into [q=c][k] swizzled LDS image (same image as before) -> PV path unchanged.
__global__ __launch_bounds__(256) void k_attn(const u16* __restrict__ qf, const u16* __restrict__ ksw,
                                              const u16* __restrict__ vsw, u16* __restrict__ y) {
  __shared__ __align__(16) u16 kvbuf[2][2][8192]; // [buf][K=0/V=1][16KB]
  __shared__ __align__(16) char plds_all[4][2048];
  int tid = threadIdx.x, wid = tid >> 6, lane = tid & 63;
  int g = lane >> 4, c = lane & 15;
  int task = (blockIdx.x & 7) * 128 + (blockIdx.x >> 3);
  int bh = task >> 5;
  int qb = 31 - (task & 31);            // heavy-first within head
  int nt = qb + 1;
  int q0 = qb * 64 + wid * 16;
  const u16* qp = qf + (size_t)bh * TSEQ * 128;
  const u16* kswb = ksw + (size_t)bh * 32 * 8192;
  const u16* vswb = vsw + (size_t)bh * 32 * 8192;
  char* plds = plds_all[wid];
  int swz = (c & 7) << 4;
  bf16x8 qfr[4];
#pragma unroll
  for (int kc = 0; kc < 4; kc++)
    qfr[kc] = *(const bf16x8*)(qp + (size_t)(q0 + c) * 128 + kc * 32 + g * 8);
  f32x4 oacc[8];
#pragma unroll
  for (int nd = 0; nd < 8; nd++) oacc[nd] = (f32x4){0, 0, 0, 0};
  float mreg = -1e30f, lreg = 0.f;
  int qrow = q0 + c;
  int chunk = wid * 4;
#pragma unroll
  for (int j = 0; j < 4; j++) {
    GLD16(kswb + (chunk + j) * 512 + lane * 8, &kvbuf[0][0][(chunk + j) * 512]);
    GLD16(vswb + (chunk + j) * 512 + lane * 8, &kvbuf[0][1][(chunk + j) * 512]);
  }
  __syncthreads();
  for (int it = 0; it < nt; it++) {
    int cur = it & 1;
    if (it + 1 < nt) {
      const u16* kt = kswb + (size_t)(it + 1) * 8192;
      const u16* vt = vswb + (size_t)(it + 1) * 8192;
#pragma unroll
      for (int j = 0; j < 4; j++) {
        GLD16(kt + (chunk + j) * 512 + lane * 8, &kvbuf[cur ^ 1][0][(chunk + j) * 512]);
        GLD16(vt + (chunk + j) * 512 + lane * 8, &kvbuf[cur ^ 1][1][(chunk + j) * 512]);
      }
    }
    const char* Kt = (const char*)kvbuf[cur][0];
    const char* Vt = (const char*)kvbuf[cur][1];
    int kt0 = it * 64;
    bool maskit = (it == nt - 1);
    // QK^T, swapped operands: sacc[s][r] = S[k=s*16+g*4+r][q=c]
    f32x4 sacc[4];
#pragma unroll
    for (int s = 0; s < 4; s++) sacc[s] = (f32x4){0, 0, 0, 0};
#pragma unroll
    for (int s = 0; s < 4; s++) {
      int row = s * 16 + c;
#pragma unroll
      for (int kc = 0; kc < 4; kc++) {
        int a = (row * 256 + (kc * 32 + g * 8) * 2) ^ ((row & 7) << 4);
        bf16x8 kfr = *(const bf16x8*)(Kt + a);
        sacc[s] = __builtin_amdgcn_mfma_f32_16x16x32_bf16(kfr, qfr[kc], sacc[s], 0, 0, 0);
      }
    }
    if (maskit) {
#pragma unroll
      for (int s = 0; s < 4; s++)
#pragma unroll
        for (int r = 0; r < 4; r++) {
          int key = kt0 + s * 16 + g * 4 + r;
          sacc[s][r] = (key <= qrow) ? sacc[s][r] : -3e38f;
        }
    }
    // lane-local softmax for q-row c (quad-reduce across lanes c, c+16, c+32, c+48)
    float mx = sacc[0][0];
#pragma unroll
    for (int s = 0; s < 4; s++)
#pragma unroll
      for (int r = 0; r < 4; r++) mx = fmaxf(mx, sacc[s][r]);
    mx = fmaxf(mx, __shfl_xor(mx, 16, 64));
    mx = fmaxf(mx, __shfl_xor(mx, 32, 64));
    float mn = fmaxf(mreg, mx);
    float fac = __expf(mreg - mn);
    float p[4][4];
    float rs = 0.f;
#pragma unroll
    for (int s = 0; s < 4; s++)
#pragma unroll
      for (int r = 0; r < 4; r++) {
        p[s][r] = __expf(sacc[s][r] - mn);
        rs += p[s][r];
      }
    rs += __shfl_xor(rs, 16, 64);
    rs += __shfl_xor(rs, 32, 64);
    lreg = lreg * fac + rs;
    mreg = mn;
    // rescale O (rows q = g*4 + r need f from lane g*4+r)
    float fq[4];
#pragma unroll
    for (int r = 0; r < 4; r++) fq[r] = __shfl(fac, g * 4 + r, 64);
#pragma unroll
    for (int nd = 0; nd < 8; nd++)
#pragma unroll
      for (int r = 0; r < 4; r++) oacc[nd][r] *= fq[r];
    // pack P -> LDS [q=c][k] swizzled (4 x 8B writes)
#pragma unroll
    for (int s = 0; s < 4; s++) {
      u32 w0 = cvtpk(p[s][0], p[s][1]);
      u32 w1 = cvtpk(p[s][2], p[s][3]);
      int a = (c * 128 + s * 32 + g * 8) ^ swz;
      *(uint2*)(plds + a) = make_uint2(w0, w1);
    }
    // PV: pa = P[q=c][k=kc2*32+g*8 ..+7], vfr = V^T rows d=nd*16+c
#pragma unroll
    for (int kc2 = 0; kc2 < 2; kc2++) {
      int a2 = (c * 128 + kc2 * 64 + g * 16) ^ swz;
      bf16x8 pa = *(const bf16x8*)(plds + a2);
#pragma unroll
      for (int nd = 0; nd < 8; nd++) {
        int vrow = nd * 16 + c;
        int av = (vrow * 128 + (kc2 * 32 + g * 8) * 2) ^ ((vrow & 7) << 4);
        bf16x8 vfr = *(const bf16x8*)(Vt + av);
        oacc[nd] = __builtin_amdgcn_mfma_f32_16x16x32_bf16(pa, vfr, oacc[nd], 0, 0, 0);
      }
    }
    __syncthreads();
  }
  int b2 = bh >> 4, h2 = bh & 15;
  float linv = 1.f / lreg;
  float inv[4];
#pragma unroll
  for (int r = 0; r < 4; r++) inv[r] = __shfl(linv, g * 4 + r, 64);
#pragma unroll
  for (int nd = 0; nd < 8; nd++) {
#pragma unroll
    for (int r = 0; r < 4; r++) {
      size_t offo = ((size_t)(b2 * TSEQ + q0 + g * 4 + r)) * 2048 + h2 * 128 + nd * 16 + c;
      y[offo] = f2bf(oacc[nd][r] * inv[r]);
    }
  }
}

extern "C" void kernel_launch(void* const* d_in, const int* in_sizes, int n_in,
                              void* d_out, int out_size, void* d_ws, size_t ws_size,
                              hipStream_t stream) {
  (void)in_sizes; (void)n_in; (void)out_size; (void)ws_size;
  const float* x      = (const float*)d_in[0];
  const float* ve     = (const float*)d_in[1];
  const float* cosp   = (const float*)d_in[2];
  const float* sinp   = (const float*)d_in[3];
  const float* w_dkv  = (const float*)d_in[4];
  const float* w_ukv  = (const float*)d_in[5];
  const float* w_kr   = (const float*)d_in[6];
  const float* w_dq   = (const float*)d_in[7];
  const float* w_q    = (const float*)d_in[8];
  const float* w_cp   = (const float*)d_in[9];
  const float* w_vg   = (const float*)d_in[10];
  float* out = (float*)d_out;   // reference output dtype is float32

  char* ws = (char*)d_ws;
  size_t off = 0;
  auto alloc = [&](size_t bytes) -> char* {
    char* p = ws + off;
    off += (bytes + 255) & ~(size_t)255;
    return p;
  };
  u16* xb     = (u16*)alloc(4096ull * 2048 * 2);
  u16* wdkvT  = (u16*)alloc(768ull * 2048 * 2);
  u16* wukvT  = (u16*)alloc(3072ull * 768 * 2);
  u16* wkrT   = (u16*)alloc(64ull * 2048 * 2);
  u16* wdqT   = (u16*)alloc(768ull * 2048 * 2);
  u16* wqT    = (u16*)alloc(2048ull * 768 * 2);
  u16* wcpT   = (u16*)alloc(2048ull * 2048 * 2);
  u16* ckv    = (u16*)alloc(4096ull * 768 * 2);
  u16* kvb    = (u16*)alloc(4096ull * 3072 * 2);
  u16* q1b    = (u16*)alloc(4096ull * 768 * 2);
  u16* qrawb  = (u16*)alloc(4096ull * 2048 * 2);
  u16* krb    = (u16*)alloc(4096ull * 64 * 2);
  float* gateb = (float*)alloc(4096ull * 16 * 4);
  u16* qfb    = (u16*)alloc(2ull * 16 * 2048 * 128 * 2);
  u16* kswb   = (u16*)alloc(32ull * 32 * 8192 * 2);
  u16* vswb   = (u16*)alloc(32ull * 32 * 8192 * 2);
  u16* yb = xb; // alias: x_bf dead after q1/k_rope/gate GEMMs

  // 1. conversions
  k_conv_x<<<dim3(4096), dim3(256), 0, stream>>>(x, xb);
  k_tconv<<<dim3(64, 24), dim3(256), 0, stream>>>(w_dkv, wdkvT, 2048, 672, 2048);
  k_tconv<<<dim3(24, 96), dim3(256), 0, stream>>>(w_ukv, wukvT, 672, 3072, 768);
  k_tconv<<<dim3(64, 2),  dim3(256), 0, stream>>>(w_kr,  wkrT,  2048, 64, 2048);
  k_tconv<<<dim3(64, 24), dim3(256), 0, stream>>>(w_dq,  wdqT,  2048, 672, 2048);
  k_tconv<<<dim3(24, 64), dim3(256), 0, stream>>>(w_q,   wqT,   672, 2048, 768);
  k_tconv<<<dim3(64, 64), dim3(256), 0, stream>>>(w_cp,  wcpT,  2048, 2048, 2048);
  k_gate<<<dim3(256), dim3(256), 0, stream>>>(x, w_vg, gateb);

  // 2. projection GEMMs
  k_gemm128<u16><<<dim3(6, 32),  dim3(256), 0, stream>>>(xb,  wdkvT, ckv,   4096, 768, 2048);
  k_gemm128<u16><<<dim3(24, 32), dim3(256), 0, stream>>>(ckv, wukvT, kvb,   4096, 3072, 768);
  k_gemm_bt<u16><<<dim3(1, 64),  dim3(256), 0, stream>>>(xb,  wkrT,  krb,   4096, 64, 2048);
  k_gemm128<u16><<<dim3(6, 32),  dim3(256), 0, stream>>>(xb,  wdqT,  q1b,   4096, 768, 2048);
  k_gemm128<u16><<<dim3(16, 32), dim3(256), 0, stream>>>(q1b, wqT,   qrawb, 4096, 2048, 768);

  // 3. build q/k/v (k and v emit pre-swizzled 16KB tile images)
  k_build_k<<<dim3(1024), dim3(256), 0, stream>>>(kvb, krb, cosp, sinp, kswb);
  k_build_q<<<dim3(16384), dim3(256), 0, stream>>>(qrawb, cosp, sinp, qfb);
  k_build_v<<<dim3(1024), dim3(256), 0, stream>>>(kvb, ve, gateb, vswb);

  // 4. attention -> y (aliases xb)
  k_attn<<<dim3(1024), dim3(256), 0, stream>>>(qfb, kswb, vswb, yb);

  // 5. output projection (f32 out -> d_out)
  k_gemm128<float><<<dim3(16, 32), dim3(256), 0, stream>>>(yb, wcpT, out, 4096, 2048, 2048);
}

// Round 10
// 378.968 us; speedup vs baseline: 1.6391x; 1.1479x over previous
//
#include <hip/hip_runtime.h>
#include <hip/hip_bf16.h>

typedef unsigned short u16;
typedef unsigned int u32;
typedef __bf16 bf16x8 __attribute__((ext_vector_type(8)));
typedef float f32x4 __attribute__((ext_vector_type(4)));
typedef u16 ushort8 __attribute__((ext_vector_type(8)));

#define TSEQ 2048
#define NHEAD 16

#define GLD16(gp, lp) __builtin_amdgcn_global_load_lds( \
    (__attribute__((address_space(1))) void*)(gp), \
    (__attribute__((address_space(3))) void*)(lp), 16, 0, 0)

static __device__ __forceinline__ float bf2f(u16 u) {
  unsigned int x = ((unsigned int)u) << 16;
  union { unsigned int i; float f; } c; c.i = x; return c.f;
}
static __device__ __forceinline__ u16 f2bf(float f) {
  union { float f; unsigned int i; } c; c.f = f;
  unsigned int x = c.i;
  unsigned int r = (x + 0x7FFFu + ((x >> 16) & 1u)) >> 16;
  return (u16)r;
}
static __device__ __forceinline__ void st_out(u16* p, float v) { *p = f2bf(v); }
static __device__ __forceinline__ void st_out(float* p, float v) { *p = v; }
static __device__ __forceinline__ u32 cvtpk(float lo, float hi) {
  u32 w;
  asm("v_cvt_pk_bf16_f32 %0, %1, %2" : "=v"(w) : "v"(lo), "v"(hi));
  return w;
}

// ---------------- convert x (f32 -> bf16), 8 elems/thread ----------------
__global__ __launch_bounds__(256) void k_conv_x(const float* __restrict__ x, u16* __restrict__ xb) {
  size_t i = ((size_t)blockIdx.x * 256 + threadIdx.x) * 8;
  float4 a = *(const float4*)(x + i);
  float4 b = *(const float4*)(x + i + 4);
  ushort8 o;
  o[0] = f2bf(a.x); o[1] = f2bf(a.y); o[2] = f2bf(a.z); o[3] = f2bf(a.w);
  o[4] = f2bf(b.x); o[5] = f2bf(b.y); o[6] = f2bf(b.z); o[7] = f2bf(b.w);
  *(ushort8*)(xb + i) = o;
}

// -------- transpose+convert weight: src f32 [R,Cc] -> dst bf16, dst[c][r]=src[r][c], zero-padded --------
__global__ __launch_bounds__(256) void k_tconv(const float* __restrict__ src, u16* __restrict__ dst,
                                               int R, int Cc, int Rpad) {
  __shared__ float sm[32][33];
  int tx = threadIdx.x & 31, ty = threadIdx.x >> 5;
  int r0 = blockIdx.x * 32, c0 = blockIdx.y * 32;
#pragma unroll
  for (int i = 0; i < 4; i++) {
    int r = r0 + ty + 8 * i;
    int c = c0 + tx;
    sm[ty + 8 * i][tx] = (r < R && c < Cc) ? src[(size_t)r * Cc + c] : 0.f;
  }
  __syncthreads();
#pragma unroll
  for (int i = 0; i < 4; i++) {
    int c = c0 + ty + 8 * i;
    dst[(size_t)c * Rpad + r0 + tx] = f2bf(sm[tx][ty + 8 * i]);
  }
}

// ---------------- gate = 2*sigmoid(x[:, :32] @ w_ve_gate) ----------------
__global__ __launch_bounds__(256) void k_gate(const float* __restrict__ x, const float* __restrict__ wg,
                                              float* __restrict__ gate) {
  int idx = blockIdx.x * 256 + threadIdx.x; // m*16 + h
  int m = idx >> 4, h = idx & 15;
  const float* xr = x + (size_t)m * 2048;
  float s = 0.f;
#pragma unroll
  for (int j = 0; j < 32; j++) s += xr[j] * wg[j * 16 + h];
  gate[idx] = 2.f / (1.f + __expf(-s));
}

// ---------------- 128x128 GEMM, m97-style: linear LDS + global_load_lds w16, BK=32, strided ----------------
template <typename OT>
__global__ __launch_bounds__(256) void k_gemm128(const u16* __restrict__ A, int lda,
                                                 const u16* __restrict__ BT, int ldb,
                                                 OT* __restrict__ C, int ldc,
                                                 int K) {
  __shared__ __align__(16) u16 As[128 * 32];
  __shared__ __align__(16) u16 Bs[128 * 32];
  int t = threadIdx.x;
  int wid = t >> 6, lane = t & 63;
  int m0 = blockIdx.y * 128, n0 = blockIdx.x * 128;
  int c0 = wid * 2;
  int srow0 = c0 * 16 + (lane >> 2);
  int scol = (lane & 3) * 8;
  const u16* Ag0 = A + (size_t)(m0 + srow0) * lda + scol;
  const u16* Ag1 = A + (size_t)(m0 + srow0 + 16) * lda + scol;
  const u16* Bg0 = BT + (size_t)(n0 + srow0) * ldb + scol;
  const u16* Bg1 = BT + (size_t)(n0 + srow0 + 16) * ldb + scol;
  u16* Al0 = &As[c0 * 512];
  u16* Al1 = &As[c0 * 512 + 512];
  u16* Bl0 = &Bs[c0 * 512];
  u16* Bl1 = &Bs[c0 * 512 + 512];
  int wr = (wid >> 1) * 64, wc = (wid & 1) * 64;
  int fr = lane & 15, fo = (lane >> 4) * 8;
  f32x4 acc[4][4];
#pragma unroll
  for (int m = 0; m < 4; m++)
#pragma unroll
    for (int n = 0; n < 4; n++) acc[m][n] = (f32x4){0, 0, 0, 0};
  for (int k0 = 0; k0 < K; k0 += 32) {
    GLD16(Ag0 + k0, Al0);
    GLD16(Ag1 + k0, Al1);
    GLD16(Bg0 + k0, Bl0);
    GLD16(Bg1 + k0, Bl1);
    __syncthreads();
    bf16x8 af[4], bf[4];
#pragma unroll
    for (int m = 0; m < 4; m++) af[m] = *(const bf16x8*)&As[(wr + m * 16 + fr) * 32 + fo];
#pragma unroll
    for (int n = 0; n < 4; n++) bf[n] = *(const bf16x8*)&Bs[(wc + n * 16 + fr) * 32 + fo];
#pragma unroll
    for (int m = 0; m < 4; m++)
#pragma unroll
      for (int n = 0; n < 4; n++)
        acc[m][n] = __builtin_amdgcn_mfma_f32_16x16x32_bf16(af[m], bf[n], acc[m][n], 0, 0, 0);
    __syncthreads();
  }
  int cr = (lane >> 4) * 4, cc = lane & 15;
#pragma unroll
  for (int m = 0; m < 4; m++)
#pragma unroll
    for (int n = 0; n < 4; n++)
#pragma unroll
      for (int r = 0; r < 4; r++)
        st_out(&C[(size_t)(m0 + wr + m * 16 + cr + r) * ldc + n0 + wc + n * 16 + cc], acc[m][n][r]);
}

// ---------------- build K -> swizzled tile images ksw[bh][tile][16KB] ----------------
// kr lives in catout cols 1536.. (stride 1664).
__global__ __launch_bounds__(256) void k_build_k(const u16* __restrict__ kv, const u16* __restrict__ kr,
                                                 const float* __restrict__ cosp, const float* __restrict__ sinp,
                                                 u16* __restrict__ ksw) {
  __shared__ __align__(16) u16 sm[8192];
  int tid = threadIdx.x, wid = tid >> 6, lane = tid & 63;
  int bh = blockIdx.x >> 5, tile = blockIdx.x & 31;
  int b = bh >> 4, h = bh & 15;
  int d0 = lane * 2;
  for (int rr = 0; rr < 16; rr++) {
    int row = wid * 16 + rr;
    int t = tile * 64 + row;
    int m = b * TSEQ + t;
    float v[2];
#pragma unroll
    for (int e = 0; e < 2; e++) {
      int d = d0 + e;
      float val;
      if (d < 64) {
        val = bf2f(kv[(size_t)m * 3072 + h * 192 + d]);
      } else {
        int dd = d - 64, i = dd & 31;
        float c = cosp[m * 32 + i], s = sinp[m * 32 + i];
        float x1 = bf2f(kr[(size_t)m * 1664 + i]), x2 = bf2f(kr[(size_t)m * 1664 + 32 + i]);
        val = (dd < 32) ? (x1 * c + x2 * s) : (x2 * c - x1 * s);
      }
      v[e] = val;
    }
    float ss = v[0] * v[0] + v[1] * v[1];
#pragma unroll
    for (int o = 1; o < 64; o <<= 1) ss += __shfl_xor(ss, o, 64);
    float rms = rsqrtf(ss * (1.f / 128.f) + 1.1920929e-7f);
    int a = (row * 256 + d0 * 2) ^ ((row & 7) << 4);
    sm[a >> 1] = f2bf(v[0] * rms);
    sm[(a >> 1) + 1] = f2bf(v[1] * rms);
  }
  __syncthreads();
  u16* dst = ksw + ((size_t)(bh * 32 + tile)) * 8192 + tid * 32;
  const u16* src = sm + tid * 32;
#pragma unroll
  for (int j = 0; j < 4; j++)
    *(ushort8*)(dst + j * 8) = *(const ushort8*)(src + j * 8);
}

// ---------------- build Q: concat(q_nope, rope(q_rope)), rmsnorm * log2e/sqrt(128) ----------------
// exp2-domain: attention scores come out pre-multiplied by log2(e)/sqrt(128) -> softmax uses exp2f.
__global__ __launch_bounds__(256) void k_build_q(const u16* __restrict__ qr,
                                                 const float* __restrict__ cosp, const float* __restrict__ sinp,
                                                 u16* __restrict__ qf) {
  int wid = threadIdx.x >> 6, lane = threadIdx.x & 63;
  int idx = blockIdx.x * 4 + wid; // m*16 + h
  int m = idx >> 4, h = idx & 15;
  size_t bin = (size_t)m * 2048 + h * 128;
  int d0 = lane * 2;
  float v[2];
#pragma unroll
  for (int e = 0; e < 2; e++) {
    int d = d0 + e;
    float val;
    if (d < 64) {
      val = bf2f(qr[bin + d]);
    } else {
      int dd = d - 64, i = dd & 31;
      float c = cosp[m * 32 + i], s = sinp[m * 32 + i];
      float x1 = bf2f(qr[bin + 64 + i]), x2 = bf2f(qr[bin + 96 + i]);
      val = (dd < 32) ? (x1 * c + x2 * s) : (x2 * c - x1 * s);
    }
    v[e] = val;
  }
  float ss = v[0] * v[0] + v[1] * v[1];
#pragma unroll
  for (int o = 1; o < 64; o <<= 1) ss += __shfl_xor(ss, o, 64);
  float rms = rsqrtf(ss * (1.f / 128.f) + 1.1920929e-7f) * 0.1275174245f; // (1/sqrt128)*log2(e)
  int b = m >> 11, tt = m & 2047;
  size_t base = ((size_t)(b * NHEAD + h) * TSEQ + tt) * 128 + d0;
  qf[base] = f2bf(v[0] * rms);
  qf[base + 1] = f2bf(v[1] * rms);
}

// ---------------- build V -> swizzled tile images vsw[bh][tile][16KB] ----------------
__global__ __launch_bounds__(256) void k_build_v(const u16* __restrict__ kv, const float* __restrict__ ve,
                                                 const float* __restrict__ gate, u16* __restrict__ vsw) {
  __shared__ __align__(16) char sm[128 * 128];
  int bh = blockIdx.x >> 5, tile = blockIdx.x & 31;
  int t0 = tile * 64;
  int b = bh >> 4, h = bh & 15;
  int tt = threadIdx.x >> 2, dp = (threadIdx.x & 3) * 32;
  int m = b * TSEQ + t0 + tt;
  float g = gate[m * 16 + h];
  const u16* kvp = kv + (size_t)m * 3072 + h * 192 + 64 + dp;
  const float* vep = ve + (size_t)m * 2048 + h * 128 + dp;
  ushort8 kvv[4];
  float4 vev[8];
#pragma unroll
  for (int u = 0; u < 4; u++) kvv[u] = *(const ushort8*)(kvp + u * 8);
#pragma unroll
  for (int u = 0; u < 8; u++) vev[u] = *(const float4*)(vep + u * 4);
#pragma unroll
  for (int j = 0; j < 32; j++) {
    float vvf = ((const float*)&vev[j >> 2])[j & 3];
    float v = bf2f(kvv[j >> 3][j & 7]) + g * vvf;
    int row = dp + j;
    int a = row * 128 + tt * 2;
    *(u16*)(sm + (a ^ ((row & 7) << 4))) = f2bf(v);
  }
  __syncthreads();
  u16* dst = vsw + ((size_t)(bh * 32 + tile)) * 8192 + threadIdx.x * 32;
  const u16* src = (const u16*)sm + threadIdx.x * 32;
#pragma unroll
  for (int j = 0; j < 4; j++)
    *(ushort8*)(dst + j * 8) = *(const ushort8*)(src + j * 8);
}

// ---------------- flash attention: swapped QK^T, exp2 softmax, defer-max, staged K/V ----------------
__global__ __launch_bounds__(256) void k_attn(const u16* __restrict__ qf, const u16* __restrict__ ksw,
                                              const u16* __restrict__ vsw, u16* __restrict__ y) {
  __shared__ __align__(16) u16 kvbuf[2][2][8192]; // [buf][K=0/V=1][16KB]
  __shared__ __align__(16) char plds_all[4][2048];
  int tid = threadIdx.x, wid = tid >> 6, lane = tid & 63;
  int g = lane >> 4, c = lane & 15;
  int task = (blockIdx.x & 7) * 128 + (blockIdx.x >> 3);
  int bh = task >> 5;
  int qb = 31 - (task & 31);            // heavy-first within head
  int nt = qb + 1;
  int q0 = qb * 64 + wid * 16;
  const u16* qp = qf + (size_t)bh * TSEQ * 128;
  const u16* kswb = ksw + (size_t)bh * 32 * 8192;
  const u16* vswb = vsw + (size_t)bh * 32 * 8192;
  char* plds = plds_all[wid];
  int swz = (c & 7) << 4;
  bf16x8 qfr[4];
#pragma unroll
  for (int kc = 0; kc < 4; kc++)
    qfr[kc] = *(const bf16x8*)(qp + (size_t)(q0 + c) * 128 + kc * 32 + g * 8);
  f32x4 oacc[8];
#pragma unroll
  for (int nd = 0; nd < 8; nd++) oacc[nd] = (f32x4){0, 0, 0, 0};
  float mreg = -1e30f, lreg = 0.f;
  int qrow = q0 + c;
  int chunk = wid * 4;
#pragma unroll
  for (int j = 0; j < 4; j++) {
    GLD16(kswb + (chunk + j) * 512 + lane * 8, &kvbuf[0][0][(chunk + j) * 512]);
    GLD16(vswb + (chunk + j) * 512 + lane * 8, &kvbuf[0][1][(chunk + j) * 512]);
  }
  __syncthreads();
  for (int it = 0; it < nt; it++) {
    int cur = it & 1;
    if (it + 1 < nt) {
      const u16* kt = kswb + (size_t)(it + 1) * 8192;
      const u16* vt = vswb + (size_t)(it + 1) * 8192;
#pragma unroll
      for (int j = 0; j < 4; j++) {
        GLD16(kt + (chunk + j) * 512 + lane * 8, &kvbuf[cur ^ 1][0][(chunk + j) * 512]);
        GLD16(vt + (chunk + j) * 512 + lane * 8, &kvbuf[cur ^ 1][1][(chunk + j) * 512]);
      }
    }
    const char* Kt = (const char*)kvbuf[cur][0];
    const char* Vt = (const char*)kvbuf[cur][1];
    int kt0 = it * 64;
    bool maskit = (it == nt - 1);
    // QK^T swapped: sacc[s][r] = S[k=s*16+g*4+r][q=c] (in log2 units)
    f32x4 sacc[4];
#pragma unroll
    for (int s = 0; s < 4; s++) sacc[s] = (f32x4){0, 0, 0, 0};
    __builtin_amdgcn_s_setprio(1);
#pragma unroll
    for (int s = 0; s < 4; s++) {
      int row = s * 16 + c;
#pragma unroll
      for (int kc = 0; kc < 4; kc++) {
        int a = (row * 256 + (kc * 32 + g * 8) * 2) ^ ((row & 7) << 4);
        bf16x8 kfr = *(const bf16x8*)(Kt + a);
        sacc[s] = __builtin_amdgcn_mfma_f32_16x16x32_bf16(kfr, qfr[kc], sacc[s], 0, 0, 0);
      }
    }
    __builtin_amdgcn_s_setprio(0);
    if (maskit) {
#pragma unroll
      for (int s = 0; s < 4; s++)
#pragma unroll
        for (int r = 0; r < 4; r++) {
          int key = kt0 + s * 16 + g * 4 + r;
          sacc[s][r] = (key <= qrow) ? sacc[s][r] : -3e38f;
        }
    }
    // row max (lane tree + quad-reduce)
    float mx = sacc[0][0];
#pragma unroll
    for (int s = 0; s < 4; s++)
#pragma unroll
      for (int r = 0; r < 4; r++) mx = fmaxf(mx, sacc[s][r]);
    mx = fmaxf(mx, __shfl_xor(mx, 16, 64));
    mx = fmaxf(mx, __shfl_xor(mx, 32, 64));
    // defer-max: only rescale when some row grew by > 11 (log2 units; P bounded by 2^11)
    if (!__all(mx - mreg <= 11.f)) {
      float mn = fmaxf(mreg, mx);
      float fac = exp2f(mreg - mn);
      lreg *= fac;
      float fq[4];
#pragma unroll
      for (int r = 0; r < 4; r++) fq[r] = __shfl(fac, g * 4 + r, 64);
#pragma unroll
      for (int nd = 0; nd < 8; nd++)
#pragma unroll
        for (int r = 0; r < 4; r++) oacc[nd][r] *= fq[r];
      mreg = mn;
    }
    float p[4][4];
    float rs = 0.f;
#pragma unroll
    for (int s = 0; s < 4; s++)
#pragma unroll
      for (int r = 0; r < 4; r++) {
        p[s][r] = exp2f(sacc[s][r] - mreg);
        rs += p[s][r];
      }
    rs += __shfl_xor(rs, 16, 64);
    rs += __shfl_xor(rs, 32, 64);
    lreg += rs;
    // pack P -> LDS [q=c][k] swizzled (4 x 8B writes)
#pragma unroll
    for (int s = 0; s < 4; s++) {
      u32 w0 = cvtpk(p[s][0], p[s][1]);
      u32 w1 = cvtpk(p[s][2], p[s][3]);
      int a = (c * 128 + s * 32 + g * 8) ^ swz;
      *(uint2*)(plds + a) = make_uint2(w0, w1);
    }
    // PV
    __builtin_amdgcn_s_setprio(1);
#pragma unroll
    for (int kc2 = 0; kc2 < 2; kc2++) {
      int a2 = (c * 128 + kc2 * 64 + g * 16) ^ swz;
      bf16x8 pa = *(const bf16x8*)(plds + a2);
#pragma unroll
      for (int nd = 0; nd < 8; nd++) {
        int vrow = nd * 16 + c;
        int av = (vrow * 128 + (kc2 * 32 + g * 8) * 2) ^ ((vrow & 7) << 4);
        bf16x8 vfr = *(const bf16x8*)(Vt + av);
        oacc[nd] = __builtin_amdgcn_mfma_f32_16x16x32_bf16(pa, vfr, oacc[nd], 0, 0, 0);
      }
    }
    __builtin_amdgcn_s_setprio(0);
    __syncthreads();
  }
  int b2 = bh >> 4, h2 = bh & 15;
  float linv = 1.f / lreg;
  float inv[4];
#pragma unroll
  for (int r = 0; r < 4; r++) inv[r] = __shfl(linv, g * 4 + r, 64);
#pragma unroll
  for (int nd = 0; nd < 8; nd++) {
#pragma unroll
    for (int r = 0; r < 4; r++) {
      size_t offo = ((size_t)(b2 * TSEQ + q0 + g * 4 + r)) * 2048 + h2 * 128 + nd * 16 + c;
      y[offo] = f2bf(oacc[nd][r] * inv[r]);
    }
  }
}

extern "C" void kernel_launch(void* const* d_in, const int* in_sizes, int n_in,
                              void* d_out, int out_size, void* d_ws, size_t ws_size,
                              hipStream_t stream) {
  (void)in_sizes; (void)n_in; (void)out_size; (void)ws_size;
  const float* x      = (const float*)d_in[0];
  const float* ve     = (const float*)d_in[1];
  const float* cosp   = (const float*)d_in[2];
  const float* sinp   = (const float*)d_in[3];
  const float* w_dkv  = (const float*)d_in[4];
  const float* w_ukv  = (const float*)d_in[5];
  const float* w_kr   = (const float*)d_in[6];
  const float* w_dq   = (const float*)d_in[7];
  const float* w_q    = (const float*)d_in[8];
  const float* w_cp   = (const float*)d_in[9];
  const float* w_vg   = (const float*)d_in[10];
  float* out = (float*)d_out;   // reference output dtype is float32

  char* ws = (char*)d_ws;
  size_t off = 0;
  auto alloc = [&](size_t bytes) -> char* {
    char* p = ws + off;
    off += (bytes + 255) & ~(size_t)255;
    return p;
  };
  u16* xb     = (u16*)alloc(4096ull * 2048 * 2);
  u16* wcatT  = (u16*)alloc(1664ull * 2048 * 2);  // rows: [0,768)=dkv, [768,1536)=dq, [1536,1600)=kr, rest unused
  u16* wukvT  = (u16*)alloc(3072ull * 768 * 2);
  u16* wqT    = (u16*)alloc(2048ull * 768 * 2);
  u16* wcpT   = (u16*)alloc(2048ull * 2048 * 2);
  u16* catout = (u16*)alloc(4096ull * 1664 * 2);  // cols: [0,768)=ckv, [768,1536)=q1, [1536,1600)=kr
  u16* kvb    = (u16*)alloc(4096ull * 3072 * 2);
  u16* qrawb  = (u16*)alloc(4096ull * 2048 * 2);
  float* gateb = (float*)alloc(4096ull * 16 * 4);
  u16* qfb    = (u16*)alloc(2ull * 16 * 2048 * 128 * 2);
  u16* kswb   = (u16*)alloc(32ull * 32 * 8192 * 2);
  u16* vswb   = (u16*)alloc(32ull * 32 * 8192 * 2);
  u16* yb = xb; // alias: x_bf dead after the cat GEMM

  // 1. conversions
  k_conv_x<<<dim3(4096), dim3(256), 0, stream>>>(x, xb);
  k_tconv<<<dim3(64, 24), dim3(256), 0, stream>>>(w_dkv, wcatT,               2048, 672, 2048);
  k_tconv<<<dim3(64, 24), dim3(256), 0, stream>>>(w_dq,  wcatT + 768 * 2048,  2048, 672, 2048);
  k_tconv<<<dim3(64, 2),  dim3(256), 0, stream>>>(w_kr,  wcatT + 1536 * 2048, 2048, 64, 2048);
  k_tconv<<<dim3(24, 96), dim3(256), 0, stream>>>(w_ukv, wukvT, 672, 3072, 768);
  k_tconv<<<dim3(24, 64), dim3(256), 0, stream>>>(w_q,   wqT,   672, 2048, 768);
  k_tconv<<<dim3(64, 64), dim3(256), 0, stream>>>(w_cp,  wcpT,  2048, 2048, 2048);
  k_gate<<<dim3(256), dim3(256), 0, stream>>>(x, w_vg, gateb);

  // 2. projection GEMMs (x-projections fused into one N=1664 GEMM)
  k_gemm128<u16><<<dim3(13, 32), dim3(256), 0, stream>>>(xb, 2048, wcatT, 2048, catout, 1664, 2048);
  k_gemm128<u16><<<dim3(24, 32), dim3(256), 0, stream>>>(catout, 1664, wukvT, 768, kvb, 3072, 768);
  k_gemm128<u16><<<dim3(16, 32), dim3(256), 0, stream>>>(catout + 768, 1664, wqT, 768, qrawb, 2048, 768);

  // 3. build q/k/v (k and v emit pre-swizzled 16KB tile images)
  k_build_k<<<dim3(1024), dim3(256), 0, stream>>>(kvb, catout + 1536, cosp, sinp, kswb);
  k_build_q<<<dim3(16384), dim3(256), 0, stream>>>(qrawb, cosp, sinp, qfb);
  k_build_v<<<dim3(1024), dim3(256), 0, stream>>>(kvb, ve, gateb, vswb);

  // 4. attention -> y (aliases xb)
  k_attn<<<dim3(1024), dim3(256), 0, stream>>>(qfb, kswb, vswb, yb);

  // 5. output projection (f32 out -> d_out)
  k_gemm128<float><<<dim3(16, 32), dim3(256), 0, stream>>>(yb, 2048, wcpT, 2048, out, 2048, 2048);
}

// Round 11
// 372.635 us; speedup vs baseline: 1.6670x; 1.0170x over previous
//
#include <hip/hip_runtime.h>
#include <hip/hip_bf16.h>

typedef unsigned short u16;
typedef unsigned int u32;
typedef __bf16 bf16x8 __attribute__((ext_vector_type(8)));
typedef float f32x4 __attribute__((ext_vector_type(4)));
typedef u16 ushort8 __attribute__((ext_vector_type(8)));

#define TSEQ 2048
#define NHEAD 16

#define GLD16(gp, lp) __builtin_amdgcn_global_load_lds( \
    (__attribute__((address_space(1))) void*)(gp), \
    (__attribute__((address_space(3))) void*)(lp), 16, 0, 0)

static __device__ __forceinline__ float bf2f(u16 u) {
  unsigned int x = ((unsigned int)u) << 16;
  union { unsigned int i; float f; } c; c.i = x; return c.f;
}
static __device__ __forceinline__ u16 f2bf(float f) {
  union { float f; unsigned int i; } c; c.f = f;
  unsigned int x = c.i;
  unsigned int r = (x + 0x7FFFu + ((x >> 16) & 1u)) >> 16;
  return (u16)r;
}
static __device__ __forceinline__ void st_out(u16* p, float v) { *p = f2bf(v); }
static __device__ __forceinline__ void st_out(float* p, float v) { *p = v; }
static __device__ __forceinline__ u32 cvtpk(float lo, float hi) {
  u32 w;
  asm("v_cvt_pk_bf16_f32 %0, %1, %2" : "=v"(w) : "v"(lo), "v"(hi));
  return w;
}

// ---------------- convert x (f32 -> bf16), 8 elems/thread ----------------
__global__ __launch_bounds__(256) void k_conv_x(const float* __restrict__ x, u16* __restrict__ xb) {
  size_t i = ((size_t)blockIdx.x * 256 + threadIdx.x) * 8;
  float4 a = *(const float4*)(x + i);
  float4 b = *(const float4*)(x + i + 4);
  ushort8 o;
  o[0] = f2bf(a.x); o[1] = f2bf(a.y); o[2] = f2bf(a.z); o[3] = f2bf(a.w);
  o[4] = f2bf(b.x); o[5] = f2bf(b.y); o[6] = f2bf(b.z); o[7] = f2bf(b.w);
  *(ushort8*)(xb + i) = o;
}

// -------- transpose+convert weight: src f32 [R,Cc] -> dst bf16, dst[c][r]=src[r][c], zero-padded --------
__global__ __launch_bounds__(256) void k_tconv(const float* __restrict__ src, u16* __restrict__ dst,
                                               int R, int Cc, int Rpad) {
  __shared__ float sm[32][33];
  int tx = threadIdx.x & 31, ty = threadIdx.x >> 5;
  int r0 = blockIdx.x * 32, c0 = blockIdx.y * 32;
#pragma unroll
  for (int i = 0; i < 4; i++) {
    int r = r0 + ty + 8 * i;
    int c = c0 + tx;
    sm[ty + 8 * i][tx] = (r < R && c < Cc) ? src[(size_t)r * Cc + c] : 0.f;
  }
  __syncthreads();
#pragma unroll
  for (int i = 0; i < 4; i++) {
    int c = c0 + ty + 8 * i;
    dst[(size_t)c * Rpad + r0 + tx] = f2bf(sm[tx][ty + 8 * i]);
  }
}

// ---------------- gate = 2*sigmoid(x[:, :32] @ w_ve_gate) ----------------
__global__ __launch_bounds__(256) void k_gate(const float* __restrict__ x, const float* __restrict__ wg,
                                              float* __restrict__ gate) {
  int idx = blockIdx.x * 256 + threadIdx.x; // m*16 + h
  int m = idx >> 4, h = idx & 15;
  const float* xr = x + (size_t)m * 2048;
  float s = 0.f;
#pragma unroll
  for (int j = 0; j < 32; j++) s += xr[j] * wg[j * 16 + h];
  gate[idx] = 2.f / (1.f + __expf(-s));
}

// ---------------- 128x128 GEMM, m97-style: linear LDS + global_load_lds w16, BK=32, strided ----------------
template <typename OT>
__global__ __launch_bounds__(256) void k_gemm128(const u16* __restrict__ A, int lda,
                                                 const u16* __restrict__ BT, int ldb,
                                                 OT* __restrict__ C, int ldc,
                                                 int K) {
  __shared__ __align__(16) u16 As[128 * 32];
  __shared__ __align__(16) u16 Bs[128 * 32];
  int t = threadIdx.x;
  int wid = t >> 6, lane = t & 63;
  int m0 = blockIdx.y * 128, n0 = blockIdx.x * 128;
  int c0 = wid * 2;
  int srow0 = c0 * 16 + (lane >> 2);
  int scol = (lane & 3) * 8;
  const u16* Ag0 = A + (size_t)(m0 + srow0) * lda + scol;
  const u16* Ag1 = A + (size_t)(m0 + srow0 + 16) * lda + scol;
  const u16* Bg0 = BT + (size_t)(n0 + srow0) * ldb + scol;
  const u16* Bg1 = BT + (size_t)(n0 + srow0 + 16) * ldb + scol;
  u16* Al0 = &As[c0 * 512];
  u16* Al1 = &As[c0 * 512 + 512];
  u16* Bl0 = &Bs[c0 * 512];
  u16* Bl1 = &Bs[c0 * 512 + 512];
  int wr = (wid >> 1) * 64, wc = (wid & 1) * 64;
  int fr = lane & 15, fo = (lane >> 4) * 8;
  f32x4 acc[4][4];
#pragma unroll
  for (int m = 0; m < 4; m++)
#pragma unroll
    for (int n = 0; n < 4; n++) acc[m][n] = (f32x4){0, 0, 0, 0};
  for (int k0 = 0; k0 < K; k0 += 32) {
    GLD16(Ag0 + k0, Al0);
    GLD16(Ag1 + k0, Al1);
    GLD16(Bg0 + k0, Bl0);
    GLD16(Bg1 + k0, Bl1);
    __syncthreads();
    bf16x8 af[4], bf[4];
#pragma unroll
    for (int m = 0; m < 4; m++) af[m] = *(const bf16x8*)&As[(wr + m * 16 + fr) * 32 + fo];
#pragma unroll
    for (int n = 0; n < 4; n++) bf[n] = *(const bf16x8*)&Bs[(wc + n * 16 + fr) * 32 + fo];
#pragma unroll
    for (int m = 0; m < 4; m++)
#pragma unroll
      for (int n = 0; n < 4; n++)
        acc[m][n] = __builtin_amdgcn_mfma_f32_16x16x32_bf16(af[m], bf[n], acc[m][n], 0, 0, 0);
    __syncthreads();
  }
  int cr = (lane >> 4) * 4, cc = lane & 15;
#pragma unroll
  for (int m = 0; m < 4; m++)
#pragma unroll
    for (int n = 0; n < 4; n++)
#pragma unroll
      for (int r = 0; r < 4; r++)
        st_out(&C[(size_t)(m0 + wr + m * 16 + cr + r) * ldc + n0 + wc + n * 16 + cc], acc[m][n][r]);
}

// ---------------- build K -> swizzled tile images ksw[bh][tile][16KB] ----------------
__global__ __launch_bounds__(256) void k_build_k(const u16* __restrict__ kv, const u16* __restrict__ kr,
                                                 const float* __restrict__ cosp, const float* __restrict__ sinp,
                                                 u16* __restrict__ ksw) {
  __shared__ __align__(16) u16 sm[8192];
  int tid = threadIdx.x, wid = tid >> 6, lane = tid & 63;
  int bh = blockIdx.x >> 5, tile = blockIdx.x & 31;
  int b = bh >> 4, h = bh & 15;
  int d0 = lane * 2;
  for (int rr = 0; rr < 16; rr++) {
    int row = wid * 16 + rr;
    int t = tile * 64 + row;
    int m = b * TSEQ + t;
    float v[2];
#pragma unroll
    for (int e = 0; e < 2; e++) {
      int d = d0 + e;
      float val;
      if (d < 64) {
        val = bf2f(kv[(size_t)m * 3072 + h * 192 + d]);
      } else {
        int dd = d - 64, i = dd & 31;
        float c = cosp[m * 32 + i], s = sinp[m * 32 + i];
        float x1 = bf2f(kr[(size_t)m * 1664 + i]), x2 = bf2f(kr[(size_t)m * 1664 + 32 + i]);
        val = (dd < 32) ? (x1 * c + x2 * s) : (x2 * c - x1 * s);
      }
      v[e] = val;
    }
    float ss = v[0] * v[0] + v[1] * v[1];
#pragma unroll
    for (int o = 1; o < 64; o <<= 1) ss += __shfl_xor(ss, o, 64);
    float rms = rsqrtf(ss * (1.f / 128.f) + 1.1920929e-7f);
    int a = (row * 256 + d0 * 2) ^ ((row & 7) << 4);
    sm[a >> 1] = f2bf(v[0] * rms);
    sm[(a >> 1) + 1] = f2bf(v[1] * rms);
  }
  __syncthreads();
  u16* dst = ksw + ((size_t)(bh * 32 + tile)) * 8192 + tid * 32;
  const u16* src = sm + tid * 32;
#pragma unroll
  for (int j = 0; j < 4; j++)
    *(ushort8*)(dst + j * 8) = *(const ushort8*)(src + j * 8);
}

// ---------------- build Q: concat(q_nope, rope(q_rope)), rmsnorm * log2e/sqrt(128) ----------------
__global__ __launch_bounds__(256) void k_build_q(const u16* __restrict__ qr,
                                                 const float* __restrict__ cosp, const float* __restrict__ sinp,
                                                 u16* __restrict__ qf) {
  int wid = threadIdx.x >> 6, lane = threadIdx.x & 63;
  int idx = blockIdx.x * 4 + wid; // m*16 + h
  int m = idx >> 4, h = idx & 15;
  size_t bin = (size_t)m * 2048 + h * 128;
  int d0 = lane * 2;
  float v[2];
#pragma unroll
  for (int e = 0; e < 2; e++) {
    int d = d0 + e;
    float val;
    if (d < 64) {
      val = bf2f(qr[bin + d]);
    } else {
      int dd = d - 64, i = dd & 31;
      float c = cosp[m * 32 + i], s = sinp[m * 32 + i];
      float x1 = bf2f(qr[bin + 64 + i]), x2 = bf2f(qr[bin + 96 + i]);
      val = (dd < 32) ? (x1 * c + x2 * s) : (x2 * c - x1 * s);
    }
    v[e] = val;
  }
  float ss = v[0] * v[0] + v[1] * v[1];
#pragma unroll
  for (int o = 1; o < 64; o <<= 1) ss += __shfl_xor(ss, o, 64);
  float rms = rsqrtf(ss * (1.f / 128.f) + 1.1920929e-7f) * 0.1275174245f; // (1/sqrt128)*log2(e)
  int b = m >> 11, tt = m & 2047;
  size_t base = ((size_t)(b * NHEAD + h) * TSEQ + tt) * 128 + d0;
  qf[base] = f2bf(v[0] * rms);
  qf[base + 1] = f2bf(v[1] * rms);
}

// ---------------- build V -> swizzled tile images vsw[bh][tile][16KB] ----------------
__global__ __launch_bounds__(256) void k_build_v(const u16* __restrict__ kv, const float* __restrict__ ve,
                                                 const float* __restrict__ gate, u16* __restrict__ vsw) {
  __shared__ __align__(16) char sm[128 * 128];
  int bh = blockIdx.x >> 5, tile = blockIdx.x & 31;
  int t0 = tile * 64;
  int b = bh >> 4, h = bh & 15;
  int tt = threadIdx.x >> 2, dp = (threadIdx.x & 3) * 32;
  int m = b * TSEQ + t0 + tt;
  float g = gate[m * 16 + h];
  const u16* kvp = kv + (size_t)m * 3072 + h * 192 + 64 + dp;
  const float* vep = ve + (size_t)m * 2048 + h * 128 + dp;
  ushort8 kvv[4];
  float4 vev[8];
#pragma unroll
  for (int u = 0; u < 4; u++) kvv[u] = *(const ushort8*)(kvp + u * 8);
#pragma unroll
  for (int u = 0; u < 8; u++) vev[u] = *(const float4*)(vep + u * 4);
#pragma unroll
  for (int j = 0; j < 32; j++) {
    float vvf = ((const float*)&vev[j >> 2])[j & 3];
    float v = bf2f(kvv[j >> 3][j & 7]) + g * vvf;
    int row = dp + j;
    int a = row * 128 + tt * 2;
    *(u16*)(sm + (a ^ ((row & 7) << 4))) = f2bf(v);
  }
  __syncthreads();
  u16* dst = vsw + ((size_t)(bh * 32 + tile)) * 8192 + threadIdx.x * 32;
  const u16* src = (const u16*)sm + threadIdx.x * 32;
#pragma unroll
  for (int j = 0; j < 4; j++)
    *(ushort8*)(dst + j * 8) = *(const ushort8*)(src + j * 8);
}

// ---------------- flash attention v2: 128-row blocks, 32 q-rows/wave (2 row-groups), staged K/V ----------------
// Each ds_read K/V fragment feeds TWO MFMAs (row-groups rg=0,1) -> LDS traffic per unit work halved.
__global__ __launch_bounds__(256, 2) void k_attn(const u16* __restrict__ qf, const u16* __restrict__ ksw,
                                                 const u16* __restrict__ vsw, u16* __restrict__ y) {
  __shared__ __align__(16) u16 kvbuf[2][2][8192]; // [buf][K=0/V=1][16KB]
  __shared__ __align__(16) char plds_all[4][4096]; // per wave: P [32 q][64 k] bf16, XOR-swizzled
  int tid = threadIdx.x, wid = tid >> 6, lane = tid & 63;
  int gq = lane >> 4, c = lane & 15;
  int task = (blockIdx.x & 7) * 64 + (blockIdx.x >> 3); // 512 blocks, XCD-chunked
  int bh = task >> 4;
  int qb = 15 - (task & 15);            // heavy-first within head
  int nt = 2 * qb + 2;
  int q0w = qb * 128 + wid * 32;        // this wave's 32-row base
  const u16* qp = qf + (size_t)bh * TSEQ * 128;
  const u16* kswb = ksw + (size_t)bh * 32 * 8192;
  const u16* vswb = vsw + (size_t)bh * 32 * 8192;
  char* plds = plds_all[wid];
  int swz = (c & 7) << 4;
  bf16x8 qfr[2][4];
#pragma unroll
  for (int rg = 0; rg < 2; rg++)
#pragma unroll
    for (int kc = 0; kc < 4; kc++)
      qfr[rg][kc] = *(const bf16x8*)(qp + (size_t)(q0w + rg * 16 + c) * 128 + kc * 32 + gq * 8);
  f32x4 oacc[2][8];
#pragma unroll
  for (int rg = 0; rg < 2; rg++)
#pragma unroll
    for (int nd = 0; nd < 8; nd++) oacc[rg][nd] = (f32x4){0, 0, 0, 0};
  float mreg[2] = {-1e30f, -1e30f}, lreg[2] = {0.f, 0.f};
  int chunk = wid * 4;
#pragma unroll
  for (int j = 0; j < 4; j++) {
    GLD16(kswb + (chunk + j) * 512 + lane * 8, &kvbuf[0][0][(chunk + j) * 512]);
    GLD16(vswb + (chunk + j) * 512 + lane * 8, &kvbuf[0][1][(chunk + j) * 512]);
  }
  __syncthreads();
  for (int it = 0; it < nt; it++) {
    int cur = it & 1;
    if (it + 1 < nt) {
      const u16* kt = kswb + (size_t)(it + 1) * 8192;
      const u16* vt = vswb + (size_t)(it + 1) * 8192;
#pragma unroll
      for (int j = 0; j < 4; j++) {
        GLD16(kt + (chunk + j) * 512 + lane * 8, &kvbuf[cur ^ 1][0][(chunk + j) * 512]);
        GLD16(vt + (chunk + j) * 512 + lane * 8, &kvbuf[cur ^ 1][1][(chunk + j) * 512]);
      }
    }
    int kt0 = it * 64;
    if (kt0 <= q0w + 31) { // wave-uniform skip of fully-masked tiles
      const char* Kt = (const char*)kvbuf[cur][0];
      const char* Vt = (const char*)kvbuf[cur][1];
      bool maskit = (kt0 + 63 > q0w);
      f32x4 sacc[2][4];
#pragma unroll
      for (int rg = 0; rg < 2; rg++)
#pragma unroll
        for (int s = 0; s < 4; s++) sacc[rg][s] = (f32x4){0, 0, 0, 0};
#pragma unroll
      for (int s = 0; s < 4; s++) {
        int row = s * 16 + c;
#pragma unroll
        for (int kc = 0; kc < 4; kc++) {
          int a = (row * 256 + (kc * 32 + gq * 8) * 2) ^ ((row & 7) << 4);
          bf16x8 kfr = *(const bf16x8*)(Kt + a);
          sacc[0][s] = __builtin_amdgcn_mfma_f32_16x16x32_bf16(kfr, qfr[0][kc], sacc[0][s], 0, 0, 0);
          sacc[1][s] = __builtin_amdgcn_mfma_f32_16x16x32_bf16(kfr, qfr[1][kc], sacc[1][s], 0, 0, 0);
        }
      }
      if (maskit) {
#pragma unroll
        for (int rg = 0; rg < 2; rg++) {
          int qrow = q0w + rg * 16 + c;
#pragma unroll
          for (int s = 0; s < 4; s++)
#pragma unroll
            for (int r = 0; r < 4; r++) {
              int key = kt0 + s * 16 + gq * 4 + r;
              sacc[rg][s][r] = (key <= qrow) ? sacc[rg][s][r] : -3e38f;
            }
        }
      }
      // row max per group
      float mx[2];
#pragma unroll
      for (int rg = 0; rg < 2; rg++) {
        float m2 = sacc[rg][0][0];
#pragma unroll
        for (int s = 0; s < 4; s++)
#pragma unroll
          for (int r = 0; r < 4; r++) m2 = fmaxf(m2, sacc[rg][s][r]);
        m2 = fmaxf(m2, __shfl_xor(m2, 16, 64));
        m2 = fmaxf(m2, __shfl_xor(m2, 32, 64));
        mx[rg] = m2;
      }
      bool ok = (mx[0] - mreg[0] <= 11.f) && (mx[1] - mreg[1] <= 11.f);
      if (!__all(ok)) {
#pragma unroll
        for (int rg = 0; rg < 2; rg++) {
          float mn = fmaxf(mreg[rg], mx[rg]);
          float fac = exp2f(mreg[rg] - mn);
          lreg[rg] *= fac;
          float fq[4];
#pragma unroll
          for (int r = 0; r < 4; r++) fq[r] = __shfl(fac, gq * 4 + r, 64);
#pragma unroll
          for (int nd = 0; nd < 8; nd++)
#pragma unroll
            for (int r = 0; r < 4; r++) oacc[rg][nd][r] *= fq[r];
          mreg[rg] = mn;
        }
      }
      // exp + sum + pack per group (sequential to limit register pressure)
#pragma unroll
      for (int rg = 0; rg < 2; rg++) {
        float p[4][4];
        float rs = 0.f;
#pragma unroll
        for (int s = 0; s < 4; s++)
#pragma unroll
          for (int r = 0; r < 4; r++) {
            p[s][r] = exp2f(sacc[rg][s][r] - mreg[rg]);
            rs += p[s][r];
          }
        rs += __shfl_xor(rs, 16, 64);
        rs += __shfl_xor(rs, 32, 64);
        lreg[rg] += rs;
#pragma unroll
        for (int s = 0; s < 4; s++) {
          u32 w0 = cvtpk(p[s][0], p[s][1]);
          u32 w1 = cvtpk(p[s][2], p[s][3]);
          int a = (rg * 2048 + c * 128 + s * 32 + gq * 8) ^ swz;
          *(uint2*)(plds + a) = make_uint2(w0, w1);
        }
      }
      // PV: each V fragment feeds both row-groups
#pragma unroll
      for (int kc2 = 0; kc2 < 2; kc2++) {
        int a0 = (c * 128 + kc2 * 64 + gq * 16) ^ swz;
        bf16x8 pa0 = *(const bf16x8*)(plds + a0);
        bf16x8 pa1 = *(const bf16x8*)(plds + 2048 + a0);
#pragma unroll
        for (int nd = 0; nd < 8; nd++) {
          int vrow = nd * 16 + c;
          int av = (vrow * 128 + (kc2 * 32 + gq * 8) * 2) ^ ((vrow & 7) << 4);
          bf16x8 vfr = *(const bf16x8*)(Vt + av);
          oacc[0][nd] = __builtin_amdgcn_mfma_f32_16x16x32_bf16(pa0, vfr, oacc[0][nd], 0, 0, 0);
          oacc[1][nd] = __builtin_amdgcn_mfma_f32_16x16x32_bf16(pa1, vfr, oacc[1][nd], 0, 0, 0);
        }
      }
    }
    __syncthreads();
  }
  int b2 = bh >> 4, h2 = bh & 15;
#pragma unroll
  for (int rg = 0; rg < 2; rg++) {
    float linv = 1.f / lreg[rg];
    float inv[4];
#pragma unroll
    for (int r = 0; r < 4; r++) inv[r] = __shfl(linv, gq * 4 + r, 64);
#pragma unroll
    for (int nd = 0; nd < 8; nd++) {
#pragma unroll
      for (int r = 0; r < 4; r++) {
        size_t offo = ((size_t)(b2 * TSEQ + q0w + rg * 16 + gq * 4 + r)) * 2048 + h2 * 128 + nd * 16 + c;
        y[offo] = f2bf(oacc[rg][nd][r] * inv[r]);
      }
    }
  }
}

extern "C" void kernel_launch(void* const* d_in, const int* in_sizes, int n_in,
                              void* d_out, int out_size, void* d_ws, size_t ws_size,
                              hipStream_t stream) {
  (void)in_sizes; (void)n_in; (void)out_size; (void)ws_size;
  const float* x      = (const float*)d_in[0];
  const float* ve     = (const float*)d_in[1];
  const float* cosp   = (const float*)d_in[2];
  const float* sinp   = (const float*)d_in[3];
  const float* w_dkv  = (const float*)d_in[4];
  const float* w_ukv  = (const float*)d_in[5];
  const float* w_kr   = (const float*)d_in[6];
  const float* w_dq   = (const float*)d_in[7];
  const float* w_q    = (const float*)d_in[8];
  const float* w_cp   = (const float*)d_in[9];
  const float* w_vg   = (const float*)d_in[10];
  float* out = (float*)d_out;   // reference output dtype is float32

  char* ws = (char*)d_ws;
  size_t off = 0;
  auto alloc = [&](size_t bytes) -> char* {
    char* p = ws + off;
    off += (bytes + 255) & ~(size_t)255;
    return p;
  };
  u16* xb     = (u16*)alloc(4096ull * 2048 * 2);
  u16* wcatT  = (u16*)alloc(1664ull * 2048 * 2);  // rows: [0,768)=dkv, [768,1536)=dq, [1536,1600)=kr, rest unused
  u16* wukvT  = (u16*)alloc(3072ull * 768 * 2);
  u16* wqT    = (u16*)alloc(2048ull * 768 * 2);
  u16* wcpT   = (u16*)alloc(2048ull * 2048 * 2);
  u16* catout = (u16*)alloc(4096ull * 1664 * 2);  // cols: [0,768)=ckv, [768,1536)=q1, [1536,1600)=kr
  u16* kvb    = (u16*)alloc(4096ull * 3072 * 2);
  u16* qrawb  = (u16*)alloc(4096ull * 2048 * 2);
  float* gateb = (float*)alloc(4096ull * 16 * 4);
  u16* qfb    = (u16*)alloc(2ull * 16 * 2048 * 128 * 2);
  u16* kswb   = (u16*)alloc(32ull * 32 * 8192 * 2);
  u16* vswb   = (u16*)alloc(32ull * 32 * 8192 * 2);
  u16* yb = xb; // alias: x_bf dead after the cat GEMM

  // 1. conversions
  k_conv_x<<<dim3(4096), dim3(256), 0, stream>>>(x, xb);
  k_tconv<<<dim3(64, 24), dim3(256), 0, stream>>>(w_dkv, wcatT,               2048, 672, 2048);
  k_tconv<<<dim3(64, 24), dim3(256), 0, stream>>>(w_dq,  wcatT + 768 * 2048,  2048, 672, 2048);
  k_tconv<<<dim3(64, 2),  dim3(256), 0, stream>>>(w_kr,  wcatT + 1536 * 2048, 2048, 64, 2048);
  k_tconv<<<dim3(24, 96), dim3(256), 0, stream>>>(w_ukv, wukvT, 672, 3072, 768);
  k_tconv<<<dim3(24, 64), dim3(256), 0, stream>>>(w_q,   wqT,   672, 2048, 768);
  k_tconv<<<dim3(64, 64), dim3(256), 0, stream>>>(w_cp,  wcpT,  2048, 2048, 2048);
  k_gate<<<dim3(256), dim3(256), 0, stream>>>(x, w_vg, gateb);

  // 2. projection GEMMs (x-projections fused into one N=1664 GEMM)
  k_gemm128<u16><<<dim3(13, 32), dim3(256), 0, stream>>>(xb, 2048, wcatT, 2048, catout, 1664, 2048);
  k_gemm128<u16><<<dim3(24, 32), dim3(256), 0, stream>>>(catout, 1664, wukvT, 768, kvb, 3072, 768);
  k_gemm128<u16><<<dim3(16, 32), dim3(256), 0, stream>>>(catout + 768, 1664, wqT, 768, qrawb, 2048, 768);

  // 3. build q/k/v (k and v emit pre-swizzled 16KB tile images)
  k_build_k<<<dim3(1024), dim3(256), 0, stream>>>(kvb, catout + 1536, cosp, sinp, kswb);
  k_build_q<<<dim3(16384), dim3(256), 0, stream>>>(qrawb, cosp, sinp, qfb);
  k_build_v<<<dim3(1024), dim3(256), 0, stream>>>(kvb, ve, gateb, vswb);

  // 4. attention -> y (aliases xb): 512 blocks x 4 waves x 32 rows/wave
  k_attn<<<dim3(512), dim3(256), 0, stream>>>(qfb, kswb, vswb, yb);

  // 5. output projection (f32 out -> d_out)
  k_gemm128<float><<<dim3(16, 32), dim3(256), 0, stream>>>(yb, 2048, wcpT, 2048, out, 2048, 2048);
}

// Round 12
// 339.445 us; speedup vs baseline: 1.8300x; 1.0978x over previous
//
#include <hip/hip_runtime.h>
#include <hip/hip_bf16.h>

typedef unsigned short u16;
typedef unsigned int u32;
typedef __bf16 bf16x8 __attribute__((ext_vector_type(8)));
typedef float f32x4 __attribute__((ext_vector_type(4)));
typedef u16 ushort8 __attribute__((ext_vector_type(8)));

#define TSEQ 2048
#define NHEAD 16

#define GLD16(gp, lp) __builtin_amdgcn_global_load_lds( \
    (__attribute__((address_space(1))) void*)(gp), \
    (__attribute__((address_space(3))) void*)(lp), 16, 0, 0)

static __device__ __forceinline__ float bf2f(u16 u) {
  unsigned int x = ((unsigned int)u) << 16;
  union { unsigned int i; float f; } c; c.i = x; return c.f;
}
static __device__ __forceinline__ u16 f2bf(float f) {
  union { float f; unsigned int i; } c; c.f = f;
  unsigned int x = c.i;
  unsigned int r = (x + 0x7FFFu + ((x >> 16) & 1u)) >> 16;
  return (u16)r;
}
static __device__ __forceinline__ void st_out(u16* p, float v) { *p = f2bf(v); }
static __device__ __forceinline__ void st_out(float* p, float v) { *p = v; }
static __device__ __forceinline__ u32 cvtpk(float lo, float hi) {
  u32 w;
  asm("v_cvt_pk_bf16_f32 %0, %1, %2" : "=v"(w) : "v"(lo), "v"(hi));
  return w;
}

// ---------------- convert x (f32 -> bf16), 8 elems/thread ----------------
__global__ __launch_bounds__(256) void k_conv_x(const float* __restrict__ x, u16* __restrict__ xb) {
  size_t i = ((size_t)blockIdx.x * 256 + threadIdx.x) * 8;
  float4 a = *(const float4*)(x + i);
  float4 b = *(const float4*)(x + i + 4);
  ushort8 o;
  o[0] = f2bf(a.x); o[1] = f2bf(a.y); o[2] = f2bf(a.z); o[3] = f2bf(a.w);
  o[4] = f2bf(b.x); o[5] = f2bf(b.y); o[6] = f2bf(b.z); o[7] = f2bf(b.w);
  *(ushort8*)(xb + i) = o;
}

// -------- transpose+convert weight: src f32 [R,Cc] -> dst bf16, dst[c][r]=src[r][c], zero-padded --------
__global__ __launch_bounds__(256) void k_tconv(const float* __restrict__ src, u16* __restrict__ dst,
                                               int R, int Cc, int Rpad) {
  __shared__ float sm[32][33];
  int tx = threadIdx.x & 31, ty = threadIdx.x >> 5;
  int r0 = blockIdx.x * 32, c0 = blockIdx.y * 32;
#pragma unroll
  for (int i = 0; i < 4; i++) {
    int r = r0 + ty + 8 * i;
    int c = c0 + tx;
    sm[ty + 8 * i][tx] = (r < R && c < Cc) ? src[(size_t)r * Cc + c] : 0.f;
  }
  __syncthreads();
#pragma unroll
  for (int i = 0; i < 4; i++) {
    int c = c0 + ty + 8 * i;
    dst[(size_t)c * Rpad + r0 + tx] = f2bf(sm[tx][ty + 8 * i]);
  }
}

// ---------------- gate = 2*sigmoid(x[:, :32] @ w_ve_gate) ----------------
__global__ __launch_bounds__(256) void k_gate(const float* __restrict__ x, const float* __restrict__ wg,
                                              float* __restrict__ gate) {
  int idx = blockIdx.x * 256 + threadIdx.x; // m*16 + h
  int m = idx >> 4, h = idx & 15;
  const float* xr = x + (size_t)m * 2048;
  float s = 0.f;
#pragma unroll
  for (int j = 0; j < 32; j++) s += xr[j] * wg[j * 16 + h];
  gate[idx] = 2.f / (1.f + __expf(-s));
}

// ---------------- 128x128 GEMM, m97-style: linear LDS + global_load_lds w16, BK=32, strided ----------------
template <typename OT>
__global__ __launch_bounds__(256) void k_gemm128(const u16* __restrict__ A, int lda,
                                                 const u16* __restrict__ BT, int ldb,
                                                 OT* __restrict__ C, int ldc,
                                                 int K) {
  __shared__ __align__(16) u16 As[128 * 32];
  __shared__ __align__(16) u16 Bs[128 * 32];
  int t = threadIdx.x;
  int wid = t >> 6, lane = t & 63;
  int m0 = blockIdx.y * 128, n0 = blockIdx.x * 128;
  int c0 = wid * 2;
  int srow0 = c0 * 16 + (lane >> 2);
  int scol = (lane & 3) * 8;
  const u16* Ag0 = A + (size_t)(m0 + srow0) * lda + scol;
  const u16* Ag1 = A + (size_t)(m0 + srow0 + 16) * lda + scol;
  const u16* Bg0 = BT + (size_t)(n0 + srow0) * ldb + scol;
  const u16* Bg1 = BT + (size_t)(n0 + srow0 + 16) * ldb + scol;
  u16* Al0 = &As[c0 * 512];
  u16* Al1 = &As[c0 * 512 + 512];
  u16* Bl0 = &Bs[c0 * 512];
  u16* Bl1 = &Bs[c0 * 512 + 512];
  int wr = (wid >> 1) * 64, wc = (wid & 1) * 64;
  int fr = lane & 15, fo = (lane >> 4) * 8;
  f32x4 acc[4][4];
#pragma unroll
  for (int m = 0; m < 4; m++)
#pragma unroll
    for (int n = 0; n < 4; n++) acc[m][n] = (f32x4){0, 0, 0, 0};
  for (int k0 = 0; k0 < K; k0 += 32) {
    GLD16(Ag0 + k0, Al0);
    GLD16(Ag1 + k0, Al1);
    GLD16(Bg0 + k0, Bl0);
    GLD16(Bg1 + k0, Bl1);
    __syncthreads();
    bf16x8 af[4], bf[4];
#pragma unroll
    for (int m = 0; m < 4; m++) af[m] = *(const bf16x8*)&As[(wr + m * 16 + fr) * 32 + fo];
#pragma unroll
    for (int n = 0; n < 4; n++) bf[n] = *(const bf16x8*)&Bs[(wc + n * 16 + fr) * 32 + fo];
#pragma unroll
    for (int m = 0; m < 4; m++)
#pragma unroll
      for (int n = 0; n < 4; n++)
        acc[m][n] = __builtin_amdgcn_mfma_f32_16x16x32_bf16(af[m], bf[n], acc[m][n], 0, 0, 0);
    __syncthreads();
  }
  int cr = (lane >> 4) * 4, cc = lane & 15;
#pragma unroll
  for (int m = 0; m < 4; m++)
#pragma unroll
    for (int n = 0; n < 4; n++)
#pragma unroll
      for (int r = 0; r < 4; r++)
        st_out(&C[(size_t)(m0 + wr + m * 16 + cr + r) * ldc + n0 + wc + n * 16 + cc], acc[m][n][r]);
}

// ---------------- dual GEMM: blocks [0,24) -> kv = catout[:, :768] @ wukvT  (plain epilogue)
//                  blocks [24,40) -> q = catout[:,768:1536] @ wqT, FUSED rope+rmsnorm epilogue -> qf
__global__ __launch_bounds__(256) void k_gemm_dual(const u16* __restrict__ catout,
                                                   const u16* __restrict__ wukvT,
                                                   u16* __restrict__ kvb,
                                                   const u16* __restrict__ wqT,
                                                   const float* __restrict__ cosp,
                                                   const float* __restrict__ sinp,
                                                   u16* __restrict__ qf) {
  __shared__ __align__(16) u16 As[128 * 32];
  __shared__ __align__(16) u16 Bs[128 * 32];
  int t = threadIdx.x;
  int wid = t >> 6, lane = t & 63;
  int bx = blockIdx.x;
  bool isq = (bx >= 24);
  int nx = isq ? bx - 24 : bx;
  int m0 = blockIdx.y * 128, n0 = nx * 128;
  const u16* A = isq ? catout + 768 : catout;
  const u16* BT = isq ? wqT : wukvT;
  int c0 = wid * 2;
  int srow0 = c0 * 16 + (lane >> 2);
  int scol = (lane & 3) * 8;
  const u16* Ag0 = A + (size_t)(m0 + srow0) * 1664 + scol;
  const u16* Ag1 = A + (size_t)(m0 + srow0 + 16) * 1664 + scol;
  const u16* Bg0 = BT + (size_t)(n0 + srow0) * 768 + scol;
  const u16* Bg1 = BT + (size_t)(n0 + srow0 + 16) * 768 + scol;
  u16* Al0 = &As[c0 * 512];
  u16* Al1 = &As[c0 * 512 + 512];
  u16* Bl0 = &Bs[c0 * 512];
  u16* Bl1 = &Bs[c0 * 512 + 512];
  int wr = (wid >> 1) * 64, wc = (wid & 1) * 64;
  int fr = lane & 15, fo = (lane >> 4) * 8;
  f32x4 acc[4][4];
#pragma unroll
  for (int m = 0; m < 4; m++)
#pragma unroll
    for (int n = 0; n < 4; n++) acc[m][n] = (f32x4){0, 0, 0, 0};
  for (int k0 = 0; k0 < 768; k0 += 32) {
    GLD16(Ag0 + k0, Al0);
    GLD16(Ag1 + k0, Al1);
    GLD16(Bg0 + k0, Bl0);
    GLD16(Bg1 + k0, Bl1);
    __syncthreads();
    bf16x8 af[4], bf[4];
#pragma unroll
    for (int m = 0; m < 4; m++) af[m] = *(const bf16x8*)&As[(wr + m * 16 + fr) * 32 + fo];
#pragma unroll
    for (int n = 0; n < 4; n++) bf[n] = *(const bf16x8*)&Bs[(wc + n * 16 + fr) * 32 + fo];
#pragma unroll
    for (int m = 0; m < 4; m++)
#pragma unroll
      for (int n = 0; n < 4; n++)
        acc[m][n] = __builtin_amdgcn_mfma_f32_16x16x32_bf16(af[m], bf[n], acc[m][n], 0, 0, 0);
    __syncthreads();
  }
  int cr = (lane >> 4) * 4, cc = lane & 15;
  if (!isq) {
#pragma unroll
    for (int m = 0; m < 4; m++)
#pragma unroll
      for (int n = 0; n < 4; n++)
#pragma unroll
        for (int r = 0; r < 4; r++)
          kvb[(size_t)(m0 + wr + m * 16 + cr + r) * 3072 + n0 + wc + n * 16 + cc] = f2bf(acc[m][n][r]);
    return;
  }
  // ---- fused build_q epilogue: rope on cols 64..127 (wc-half 1), rmsnorm over 128, *log2e/sqrt(128) ----
  int h = nx;            // this tile's head
  int wch = wid & 1;     // 0: cols 0..63, 1: cols 64..127
  int wrg = wid >> 1;
  if (wch == 1) {
#pragma unroll
    for (int m = 0; m < 4; m++)
#pragma unroll
      for (int r = 0; r < 4; r++) {
        int grow = m0 + wr + m * 16 + cr + r;
#pragma unroll
        for (int n = 0; n < 2; n++) {
          int i = n * 16 + cc;
          float cth = cosp[(size_t)grow * 32 + i];
          float sth = sinp[(size_t)grow * 32 + i];
          float x1 = acc[m][n][r], x2 = acc[m][n + 2][r];
          acc[m][n][r]     = x1 * cth + x2 * sth;
          acc[m][n + 2][r] = x2 * cth - x1 * sth;
        }
      }
  }
  // per-row sum of squares over this wave's 64 cols
  float part[4][4];
#pragma unroll
  for (int m = 0; m < 4; m++)
#pragma unroll
    for (int r = 0; r < 4; r++) {
      float s2 = 0.f;
#pragma unroll
      for (int n = 0; n < 4; n++) s2 += acc[m][n][r] * acc[m][n][r];
#pragma unroll
      for (int o = 1; o < 16; o <<= 1) s2 += __shfl_xor(s2, o, 64);
      part[m][r] = s2;
    }
  float* xs = (float*)As; // reuse (all ds_reads of the loop are behind its final barrier)
  if (cc == 0) {
#pragma unroll
    for (int m = 0; m < 4; m++)
#pragma unroll
      for (int r = 0; r < 4; r++)
        xs[(wrg * 2 + wch) * 64 + m * 16 + cr + r] = part[m][r];
  }
  __syncthreads();
#pragma unroll
  for (int m = 0; m < 4; m++)
#pragma unroll
    for (int r = 0; r < 4; r++) {
      int lrow = m * 16 + cr + r;
      float tot = part[m][r] + xs[(wrg * 2 + (wch ^ 1)) * 64 + lrow];
      float rms = rsqrtf(tot * (1.f / 128.f) + 1.1920929e-7f) * 0.1275174245f; // *(log2e/sqrt128)
      int grow = m0 + wr + lrow;
      int b2 = grow >> 11, tt = grow & 2047;
      size_t base = (((size_t)(b2 * NHEAD + h)) * TSEQ + tt) * 128 + wch * 64;
#pragma unroll
      for (int n = 0; n < 4; n++)
        qf[base + n * 16 + cc] = f2bf(acc[m][n][r] * rms);
    }
}

// ---------------- build K -> swizzled tile images ksw[bh][tile][16KB] ----------------
__global__ __launch_bounds__(256) void k_build_k(const u16* __restrict__ kv, const u16* __restrict__ kr,
                                                 const float* __restrict__ cosp, const float* __restrict__ sinp,
                                                 u16* __restrict__ ksw) {
  __shared__ __align__(16) u16 sm[8192];
  int tid = threadIdx.x, wid = tid >> 6, lane = tid & 63;
  int bh = blockIdx.x >> 5, tile = blockIdx.x & 31;
  int b = bh >> 4, h = bh & 15;
  int d0 = lane * 2;
  for (int rr = 0; rr < 16; rr++) {
    int row = wid * 16 + rr;
    int t = tile * 64 + row;
    int m = b * TSEQ + t;
    float v[2];
#pragma unroll
    for (int e = 0; e < 2; e++) {
      int d = d0 + e;
      float val;
      if (d < 64) {
        val = bf2f(kv[(size_t)m * 3072 + h * 192 + d]);
      } else {
        int dd = d - 64, i = dd & 31;
        float c = cosp[m * 32 + i], s = sinp[m * 32 + i];
        float x1 = bf2f(kr[(size_t)m * 1664 + i]), x2 = bf2f(kr[(size_t)m * 1664 + 32 + i]);
        val = (dd < 32) ? (x1 * c + x2 * s) : (x2 * c - x1 * s);
      }
      v[e] = val;
    }
    float ss = v[0] * v[0] + v[1] * v[1];
#pragma unroll
    for (int o = 1; o < 64; o <<= 1) ss += __shfl_xor(ss, o, 64);
    float rms = rsqrtf(ss * (1.f / 128.f) + 1.1920929e-7f);
    int a = (row * 256 + d0 * 2) ^ ((row & 7) << 4);
    sm[a >> 1] = f2bf(v[0] * rms);
    sm[(a >> 1) + 1] = f2bf(v[1] * rms);
  }
  __syncthreads();
  u16* dst = ksw + ((size_t)(bh * 32 + tile)) * 8192 + tid * 32;
  const u16* src = sm + tid * 32;
#pragma unroll
  for (int j = 0; j < 4; j++)
    *(ushort8*)(dst + j * 8) = *(const ushort8*)(src + j * 8);
}

// ---------------- build V -> swizzled tile images vsw[bh][tile][16KB] ----------------
__global__ __launch_bounds__(256) void k_build_v(const u16* __restrict__ kv, const float* __restrict__ ve,
                                                 const float* __restrict__ gate, u16* __restrict__ vsw) {
  __shared__ __align__(16) char sm[128 * 128];
  int bh = blockIdx.x >> 5, tile = blockIdx.x & 31;
  int t0 = tile * 64;
  int b = bh >> 4, h = bh & 15;
  int tt = threadIdx.x >> 2, dp = (threadIdx.x & 3) * 32;
  int m = b * TSEQ + t0 + tt;
  float g = gate[m * 16 + h];
  const u16* kvp = kv + (size_t)m * 3072 + h * 192 + 64 + dp;
  const float* vep = ve + (size_t)m * 2048 + h * 128 + dp;
  ushort8 kvv[4];
  float4 vev[8];
#pragma unroll
  for (int u = 0; u < 4; u++) kvv[u] = *(const ushort8*)(kvp + u * 8);
#pragma unroll
  for (int u = 0; u < 8; u++) vev[u] = *(const float4*)(vep + u * 4);
#pragma unroll
  for (int j = 0; j < 32; j++) {
    float vvf = ((const float*)&vev[j >> 2])[j & 3];
    float v = bf2f(kvv[j >> 3][j & 7]) + g * vvf;
    int row = dp + j;
    int a = row * 128 + tt * 2;
    *(u16*)(sm + (a ^ ((row & 7) << 4))) = f2bf(v);
  }
  __syncthreads();
  u16* dst = vsw + ((size_t)(bh * 32 + tile)) * 8192 + threadIdx.x * 32;
  const u16* src = (const u16*)sm + threadIdx.x * 32;
#pragma unroll
  for (int j = 0; j < 4; j++)
    *(ushort8*)(dst + j * 8) = *(const ushort8*)(src + j * 8);
}

// ---------------- flash attention v2: 128-row blocks, 32 q-rows/wave, staged K/V, balanced qb ----------------
__global__ __launch_bounds__(256, 2) void k_attn(const u16* __restrict__ qf, const u16* __restrict__ ksw,
                                                 const u16* __restrict__ vsw, u16* __restrict__ y) {
  __shared__ __align__(16) u16 kvbuf[2][2][8192]; // [buf][K=0/V=1][16KB]
  __shared__ __align__(16) char plds_all[4][4096]; // per wave: P [32 q][64 k] bf16, XOR-swizzled
  int tid = threadIdx.x, wid = tid >> 6, lane = tid & 63;
  int gq = lane >> 4, c = lane & 15;
  int task = (blockIdx.x & 7) * 64 + (blockIdx.x >> 3); // 512 blocks, XCD-chunked
  int bh = task >> 4;
  int tq = task & 15;
  int qb = ((task >> 5) & 1) ? tq : 15 - tq; // complementary pairing: blocks i,i+256 -> qb x,15-x (same CU)
  int nt = 2 * qb + 2;
  int q0w = qb * 128 + wid * 32;        // this wave's 32-row base
  const u16* qp = qf + (size_t)bh * TSEQ * 128;
  const u16* kswb = ksw + (size_t)bh * 32 * 8192;
  const u16* vswb = vsw + (size_t)bh * 32 * 8192;
  char* plds = plds_all[wid];
  int swz = (c & 7) << 4;
  bf16x8 qfr[2][4];
#pragma unroll
  for (int rg = 0; rg < 2; rg++)
#pragma unroll
    for (int kc = 0; kc < 4; kc++)
      qfr[rg][kc] = *(const bf16x8*)(qp + (size_t)(q0w + rg * 16 + c) * 128 + kc * 32 + gq * 8);
  f32x4 oacc[2][8];
#pragma unroll
  for (int rg = 0; rg < 2; rg++)
#pragma unroll
    for (int nd = 0; nd < 8; nd++) oacc[rg][nd] = (f32x4){0, 0, 0, 0};
  float mreg[2] = {-1e30f, -1e30f}, lreg[2] = {0.f, 0.f};
  int chunk = wid * 4;
#pragma unroll
  for (int j = 0; j < 4; j++) {
    GLD16(kswb + (chunk + j) * 512 + lane * 8, &kvbuf[0][0][(chunk + j) * 512]);
    GLD16(vswb + (chunk + j) * 512 + lane * 8, &kvbuf[0][1][(chunk + j) * 512]);
  }
  __syncthreads();
  for (int it = 0; it < nt; it++) {
    int cur = it & 1;
    if (it + 1 < nt) {
      const u16* kt = kswb + (size_t)(it + 1) * 8192;
      const u16* vt = vswb + (size_t)(it + 1) * 8192;
#pragma unroll
      for (int j = 0; j < 4; j++) {
        GLD16(kt + (chunk + j) * 512 + lane * 8, &kvbuf[cur ^ 1][0][(chunk + j) * 512]);
        GLD16(vt + (chunk + j) * 512 + lane * 8, &kvbuf[cur ^ 1][1][(chunk + j) * 512]);
      }
    }
    int kt0 = it * 64;
    if (kt0 <= q0w + 31) { // wave-uniform skip of fully-masked tiles
      const char* Kt = (const char*)kvbuf[cur][0];
      const char* Vt = (const char*)kvbuf[cur][1];
      bool maskit = (kt0 + 63 > q0w);
      f32x4 sacc[2][4];
#pragma unroll
      for (int rg = 0; rg < 2; rg++)
#pragma unroll
        for (int s = 0; s < 4; s++) sacc[rg][s] = (f32x4){0, 0, 0, 0};
#pragma unroll
      for (int s = 0; s < 4; s++) {
        int row = s * 16 + c;
#pragma unroll
        for (int kc = 0; kc < 4; kc++) {
          int a = (row * 256 + (kc * 32 + gq * 8) * 2) ^ ((row & 7) << 4);
          bf16x8 kfr = *(const bf16x8*)(Kt + a);
          sacc[0][s] = __builtin_amdgcn_mfma_f32_16x16x32_bf16(kfr, qfr[0][kc], sacc[0][s], 0, 0, 0);
          sacc[1][s] = __builtin_amdgcn_mfma_f32_16x16x32_bf16(kfr, qfr[1][kc], sacc[1][s], 0, 0, 0);
        }
      }
      if (maskit) {
#pragma unroll
        for (int rg = 0; rg < 2; rg++) {
          int qrow = q0w + rg * 16 + c;
#pragma unroll
          for (int s = 0; s < 4; s++)
#pragma unroll
            for (int r = 0; r < 4; r++) {
              int key = kt0 + s * 16 + gq * 4 + r;
              sacc[rg][s][r] = (key <= qrow) ? sacc[rg][s][r] : -3e38f;
            }
        }
      }
      float mx[2];
#pragma unroll
      for (int rg = 0; rg < 2; rg++) {
        float m2 = sacc[rg][0][0];
#pragma unroll
        for (int s = 0; s < 4; s++)
#pragma unroll
          for (int r = 0; r < 4; r++) m2 = fmaxf(m2, sacc[rg][s][r]);
        m2 = fmaxf(m2, __shfl_xor(m2, 16, 64));
        m2 = fmaxf(m2, __shfl_xor(m2, 32, 64));
        mx[rg] = m2;
      }
      bool ok = (mx[0] - mreg[0] <= 11.f) && (mx[1] - mreg[1] <= 11.f);
      if (!__all(ok)) {
#pragma unroll
        for (int rg = 0; rg < 2; rg++) {
          float mn = fmaxf(mreg[rg], mx[rg]);
          float fac = exp2f(mreg[rg] - mn);
          lreg[rg] *= fac;
          float fq[4];
#pragma unroll
          for (int r = 0; r < 4; r++) fq[r] = __shfl(fac, gq * 4 + r, 64);
#pragma unroll
          for (int nd = 0; nd < 8; nd++)
#pragma unroll
            for (int r = 0; r < 4; r++) oacc[rg][nd][r] *= fq[r];
          mreg[rg] = mn;
        }
      }
#pragma unroll
      for (int rg = 0; rg < 2; rg++) {
        float p[4][4];
        float rs = 0.f;
#pragma unroll
        for (int s = 0; s < 4; s++)
#pragma unroll
          for (int r = 0; r < 4; r++) {
            p[s][r] = exp2f(sacc[rg][s][r] - mreg[rg]);
            rs += p[s][r];
          }
        rs += __shfl_xor(rs, 16, 64);
        rs += __shfl_xor(rs, 32, 64);
        lreg[rg] += rs;
#pragma unroll
        for (int s = 0; s < 4; s++) {
          u32 w0 = cvtpk(p[s][0], p[s][1]);
          u32 w1 = cvtpk(p[s][2], p[s][3]);
          int a = (rg * 2048 + c * 128 + s * 32 + gq * 8) ^ swz;
          *(uint2*)(plds + a) = make_uint2(w0, w1);
        }
      }
#pragma unroll
      for (int kc2 = 0; kc2 < 2; kc2++) {
        int a0 = (c * 128 + kc2 * 64 + gq * 16) ^ swz;
        bf16x8 pa0 = *(const bf16x8*)(plds + a0);
        bf16x8 pa1 = *(const bf16x8*)(plds + 2048 + a0);
#pragma unroll
        for (int nd = 0; nd < 8; nd++) {
          int vrow = nd * 16 + c;
          int av = (vrow * 128 + (kc2 * 32 + gq * 8) * 2) ^ ((vrow & 7) << 4);
          bf16x8 vfr = *(const bf16x8*)(Vt + av);
          oacc[0][nd] = __builtin_amdgcn_mfma_f32_16x16x32_bf16(pa0, vfr, oacc[0][nd], 0, 0, 0);
          oacc[1][nd] = __builtin_amdgcn_mfma_f32_16x16x32_bf16(pa1, vfr, oacc[1][nd], 0, 0, 0);
        }
      }
    }
    __syncthreads();
  }
  int b2 = bh >> 4, h2 = bh & 15;
#pragma unroll
  for (int rg = 0; rg < 2; rg++) {
    float linv = 1.f / lreg[rg];
    float inv[4];
#pragma unroll
    for (int r = 0; r < 4; r++) inv[r] = __shfl(linv, gq * 4 + r, 64);
#pragma unroll
    for (int nd = 0; nd < 8; nd++) {
#pragma unroll
      for (int r = 0; r < 4; r++) {
        size_t offo = ((size_t)(b2 * TSEQ + q0w + rg * 16 + gq * 4 + r)) * 2048 + h2 * 128 + nd * 16 + c;
        y[offo] = f2bf(oacc[rg][nd][r] * inv[r]);
      }
    }
  }
}

extern "C" void kernel_launch(void* const* d_in, const int* in_sizes, int n_in,
                              void* d_out, int out_size, void* d_ws, size_t ws_size,
                              hipStream_t stream) {
  (void)in_sizes; (void)n_in; (void)out_size; (void)ws_size;
  const float* x      = (const float*)d_in[0];
  const float* ve     = (const float*)d_in[1];
  const float* cosp   = (const float*)d_in[2];
  const float* sinp   = (const float*)d_in[3];
  const float* w_dkv  = (const float*)d_in[4];
  const float* w_ukv  = (const float*)d_in[5];
  const float* w_kr   = (const float*)d_in[6];
  const float* w_dq   = (const float*)d_in[7];
  const float* w_q    = (const float*)d_in[8];
  const float* w_cp   = (const float*)d_in[9];
  const float* w_vg   = (const float*)d_in[10];
  float* out = (float*)d_out;   // reference output dtype is float32

  char* ws = (char*)d_ws;
  size_t off = 0;
  auto alloc = [&](size_t bytes) -> char* {
    char* p = ws + off;
    off += (bytes + 255) & ~(size_t)255;
    return p;
  };
  u16* xb     = (u16*)alloc(4096ull * 2048 * 2);
  u16* wcatT  = (u16*)alloc(1664ull * 2048 * 2);  // rows: [0,768)=dkv, [768,1536)=dq, [1536,1600)=kr
  u16* wukvT  = (u16*)alloc(3072ull * 768 * 2);
  u16* wqT    = (u16*)alloc(2048ull * 768 * 2);
  u16* wcpT   = (u16*)alloc(2048ull * 2048 * 2);
  u16* catout = (u16*)alloc(4096ull * 1664 * 2);  // cols: [0,768)=ckv, [768,1536)=q1, [1536,1600)=kr
  u16* kvb    = (u16*)alloc(4096ull * 3072 * 2);
  float* gateb = (float*)alloc(4096ull * 16 * 4);
  u16* qfb    = (u16*)alloc(2ull * 16 * 2048 * 128 * 2);
  u16* kswb   = (u16*)alloc(32ull * 32 * 8192 * 2);
  u16* vswb   = (u16*)alloc(32ull * 32 * 8192 * 2);
  u16* yb = xb; // alias: x_bf dead after the cat GEMM

  // 1. conversions
  k_conv_x<<<dim3(4096), dim3(256), 0, stream>>>(x, xb);
  k_tconv<<<dim3(64, 24), dim3(256), 0, stream>>>(w_dkv, wcatT,               2048, 672, 2048);
  k_tconv<<<dim3(64, 24), dim3(256), 0, stream>>>(w_dq,  wcatT + 768 * 2048,  2048, 672, 2048);
  k_tconv<<<dim3(64, 2),  dim3(256), 0, stream>>>(w_kr,  wcatT + 1536 * 2048, 2048, 64, 2048);
  k_tconv<<<dim3(24, 96), dim3(256), 0, stream>>>(w_ukv, wukvT, 672, 3072, 768);
  k_tconv<<<dim3(24, 64), dim3(256), 0, stream>>>(w_q,   wqT,   672, 2048, 768);
  k_tconv<<<dim3(64, 64), dim3(256), 0, stream>>>(w_cp,  wcpT,  2048, 2048, 2048);
  k_gate<<<dim3(256), dim3(256), 0, stream>>>(x, w_vg, gateb);

  // 2. projection GEMMs: cat (x-projections), then fused {ukv | q+build_q}
  k_gemm128<u16><<<dim3(13, 32), dim3(256), 0, stream>>>(xb, 2048, wcatT, 2048, catout, 1664, 2048);
  k_gemm_dual<<<dim3(40, 32), dim3(256), 0, stream>>>(catout, wukvT, kvb, wqT, cosp, sinp, qfb);

  // 3. build k/v (emit pre-swizzled 16KB tile images)
  k_build_k<<<dim3(1024), dim3(256), 0, stream>>>(kvb, catout + 1536, cosp, sinp, kswb);
  k_build_v<<<dim3(1024), dim3(256), 0, stream>>>(kvb, ve, gateb, vswb);

  // 4. attention -> y (aliases xb): 512 blocks x 4 waves x 32 rows/wave, CU-balanced
  k_attn<<<dim3(512), dim3(256), 0, stream>>>(qfb, kswb, vswb, yb);

  // 5. output projection (f32 out -> d_out)
  k_gemm128<float><<<dim3(16, 32), dim3(256), 0, stream>>>(yb, 2048, wcpT, 2048, out, 2048, 2048);
}